// Round 8
// baseline (1291.176 us; speedup 1.0000x reference)
//
#include <hip/hip_runtime.h>

#define DEV __device__ __forceinline__

typedef __bf16 bf16x8 __attribute__((ext_vector_type(8)));
typedef float f32x4 __attribute__((ext_vector_type(4)));
typedef unsigned short u16x4 __attribute__((ext_vector_type(4)));

DEV unsigned short f2bf(float f) {
    unsigned u = __builtin_bit_cast(unsigned, f);
    u += 0x7fffu + ((u >> 16) & 1u);   // round-to-nearest-even
    return (unsigned short)(u >> 16);
}

DEV float bf2f(unsigned short h) {
    unsigned u = (unsigned)h << 16;
    return __builtin_bit_cast(float, u);
}

// zero counts[N] + stats[1536]; pre-convert W1,W2 (6 mats) to bf16 [c][k];
// convert x -> xb (bf16); block 0 detects int64-vs-int32 edge_index layout.
__global__ __launch_bounds__(256) void setup_kernel(
    const int* __restrict__ ei, int* __restrict__ flag,
    int* __restrict__ counts, float* __restrict__ stats,
    const float* __restrict__ W1, const float* __restrict__ W2,
    unsigned short* __restrict__ Wt,
    const float* __restrict__ x, unsigned short* __restrict__ xb, int N)
{
    int g = blockIdx.x * 256 + threadIdx.x;
    if (g < N) counts[g] = 0;
    if (g < 1536) stats[g] = 0.f;
    if (g < 12288) {                       // 6 mats x 16 k-groups x 128 cols
        int mat = g >> 11;
        int r = g & 2047;
        int c = r & 127;
        int kg = (r >> 7) * 8;
        const float* Wsrc = (mat < 3) ? (W1 + (size_t)mat * 16384)
                                      : (W2 + (size_t)(mat - 3) * 16384);
        unsigned short o[8];
#pragma unroll
        for (int q = 0; q < 8; ++q)
            o[q] = f2bf(Wsrc[(size_t)(kg + q) * 128 + c]);
        *(uint4*)(Wt + ((size_t)mat * 128 + c) * 128 + kg) = *(const uint4*)o;
    }
    // x -> xb bf16 (8 elems/thread); N*16 threads cover N*128 elems
    if (g < N * 16) {
        size_t base = (size_t)g * 8;
        float4 a = *(const float4*)(x + base);
        float4 b = *(const float4*)(x + base + 4);
        unsigned short o[8];
        o[0] = f2bf(a.x); o[1] = f2bf(a.y); o[2] = f2bf(a.z); o[3] = f2bf(a.w);
        o[4] = f2bf(b.x); o[5] = f2bf(b.y); o[6] = f2bf(b.z); o[7] = f2bf(b.w);
        *(uint4*)(xb + base) = *(const uint4*)o;
    }
    if (blockIdx.x == 0 && threadIdx.x < 64) {
        int t = threadIdx.x;
        int v = (t < 32) ? ei[2 * t + 1] : 0;
        unsigned long long b = __ballot(v == 0);
        if (t == 0) *flag = (b == ~0ull) ? 1 : 0;
    }
}

__global__ __launch_bounds__(256) void hist_kernel(
    const int* __restrict__ ei, const int* __restrict__ i64flag,
    int* __restrict__ counts, int E)
{
    int e = blockIdx.x * 256 + threadIdx.x;
    if (e >= E) return;
    int d = (*i64flag) ? ei[2 * (size_t)E + 2 * (size_t)e] : ei[(size_t)E + e];
    atomicAdd(&counts[d], 1);
}

// block-level inclusive scan; writes per-element exclusive offsets + block totals
__global__ __launch_bounds__(256) void scan1_kernel(
    const int* __restrict__ counts, int* __restrict__ offs,
    int* __restrict__ bsum, int N)
{
    __shared__ int s[256];
    int tid = threadIdx.x;
    int i = blockIdx.x * 256 + tid;
    int c = (i < N) ? counts[i] : 0;
    s[tid] = c;
    __syncthreads();
#pragma unroll
    for (int off = 1; off < 256; off <<= 1) {
        int add = (tid >= off) ? s[tid - off] : 0;
        __syncthreads();
        s[tid] += add;
        __syncthreads();
    }
    int incl = s[tid];
    if (i < N) offs[i] = incl - c;            // exclusive within block
    if (tid == 255) bsum[blockIdx.x] = incl;  // block total
}

// parallel exclusive scan of block sums (nb <= 256 for N = 50000)
__global__ __launch_bounds__(256) void scan2_kernel(int* __restrict__ bsum, int nb)
{
    __shared__ int s[256];
    int tid = threadIdx.x;
    int v = (tid < nb) ? bsum[tid] : 0;
    s[tid] = v;
    __syncthreads();
#pragma unroll
    for (int off = 1; off < 256; off <<= 1) {
        int add = (tid >= off) ? s[tid - off] : 0;
        __syncthreads();
        s[tid] += add;
        __syncthreads();
    }
    if (tid < nb) bsum[tid] = s[tid] - v;     // exclusive
}

__global__ __launch_bounds__(256) void scan3_kernel(
    int* __restrict__ offs, const int* __restrict__ bsum,
    int* __restrict__ cursor, int N)
{
    int i = blockIdx.x * 256 + threadIdx.x;
    if (i < N) {
        int o = offs[i] + bsum[blockIdx.x];
        offs[i] = o;
        cursor[i] = o;
    }
}

// CSR scatter: srcd[slot] = src | ((dst & 63) << 16)  (src < 65536, dst-local 6b)
//              eslot[e] = slot  (for the ea permute)
__global__ __launch_bounds__(256) void scatter_kernel(
    const int* __restrict__ ei, const int* __restrict__ i64flag,
    int* __restrict__ cursor, int* __restrict__ srcd,
    int* __restrict__ eslot, int E)
{
    int e = blockIdx.x * 256 + threadIdx.x;
    if (e >= E) return;
    int s, d;
    if (*i64flag) {
        s = ei[2 * (size_t)e];
        d = ei[2 * (size_t)E + 2 * (size_t)e];
    } else {
        s = ei[e];
        d = ei[(size_t)E + e];
    }
    int pos = atomicAdd(&cursor[d], 1);
    srcd[pos] = s | ((d & 63) << 16);
    eslot[e] = pos;
}

// ea (f32, natural order) -> eab (bf16, CSR slot order). Sequential read,
// random 256B-row write (once; read back sequentially 3x by agg).
__global__ __launch_bounds__(256) void eaconv_kernel(
    const float* __restrict__ ea, const int* __restrict__ eslot,
    unsigned short* __restrict__ eab, int E)
{
    int g = blockIdx.x * 256 + threadIdx.x;    // E*16 groups of 8 elems
    if (g >= E * 16) return;
    int e = g >> 4;
    int part = (g & 15) * 8;
    size_t rb = (size_t)e * 128 + part;
    f32x4 a = __builtin_nontemporal_load((const f32x4*)(ea + rb));
    f32x4 b = __builtin_nontemporal_load((const f32x4*)(ea + rb + 4));
    u16x4 o0, o1;
    o0[0] = f2bf(a[0]); o0[1] = f2bf(a[1]); o0[2] = f2bf(a[2]); o0[3] = f2bf(a[3]);
    o1[0] = f2bf(b[0]); o1[1] = f2bf(b[1]); o1[2] = f2bf(b[2]); o1[3] = f2bf(b[3]);
    int slot = eslot[e];
    size_t wb = (size_t)slot * 128 + part;
    __builtin_nontemporal_store(o0, (u16x4*)(eab + wb));
    __builtin_nontemporal_store(o1, (u16x4*)(eab + wb + 4));
}

// xb = bf16(relu(BN(t3)))  -- prepares next layer's agg input; 8 elems/thread
__global__ __launch_bounds__(256) void xbn_kernel(
    const float* __restrict__ t3, const float* __restrict__ sum, const float* __restrict__ sq,
    const float* __restrict__ gamma, const float* __restrict__ beta,
    unsigned short* __restrict__ xb, int N)
{
    __shared__ float sc[128], sh[128];
    int tid = threadIdx.x;
    if (tid < 128) {
        float inv = 1.f / (float)N;
        float m = sum[tid] * inv;
        float v = sq[tid] * inv - m * m;
        v = fmaxf(v, 0.f);
        float rs = rsqrtf(v + 1e-5f);
        float gr = gamma[tid] * rs;
        sc[tid] = gr;
        sh[tid] = beta[tid] - m * gr;
    }
    __syncthreads();
    int g = blockIdx.x * 256 + tid;
    if (g >= N * 16) return;
    size_t base = (size_t)g * 8;
    int c0 = (g & 15) * 8;
    float4 a = *(const float4*)(t3 + base);
    float4 b = *(const float4*)(t3 + base + 4);
    unsigned short o[8];
    o[0] = f2bf(fmaxf(fmaf(a.x, sc[c0 + 0], sh[c0 + 0]), 0.f));
    o[1] = f2bf(fmaxf(fmaf(a.y, sc[c0 + 1], sh[c0 + 1]), 0.f));
    o[2] = f2bf(fmaxf(fmaf(a.z, sc[c0 + 2], sh[c0 + 2]), 0.f));
    o[3] = f2bf(fmaxf(fmaf(a.w, sc[c0 + 3], sh[c0 + 3]), 0.f));
    o[4] = f2bf(fmaxf(fmaf(b.x, sc[c0 + 4], sh[c0 + 4]), 0.f));
    o[5] = f2bf(fmaxf(fmaf(b.y, sc[c0 + 5], sh[c0 + 5]), 0.f));
    o[6] = f2bf(fmaxf(fmaf(b.z, sc[c0 + 6], sh[c0 + 6]), 0.f));
    o[7] = f2bf(fmaxf(fmaf(b.w, sc[c0 + 7], sh[c0 + 7]), 0.f));
    *(uint4*)(xb + base) = *(const uint4*)o;
}

// ---------------- aggregation: edge-parallel segmented reduce ----------------
// Block b owns nodes [64b, 64b+64) and their contiguous CSR slots. 16 half-waves
// each walk a contiguous chunk of slots: eab/srcd stream sequentially, xb is a
// random 256B-row gather, accumulation is by-key in registers (dst changes every
// ~16 slots) with rare LDS-atomic flushes into a 64x128 f32 tile. Write-out adds
// the self term xb[n] and stores t1 (bf16) once per row.
__global__ __launch_bounds__(512) void agg_kernel(
    const unsigned short* __restrict__ xb, const unsigned short* __restrict__ eab,
    const int* __restrict__ srcd, const int* __restrict__ offs,
    unsigned short* __restrict__ t1, int N, int E)
{
    __shared__ float acc[64][128];
    const int tid = threadIdx.x;
    const int n0 = blockIdx.x * 64;

    for (int i = tid; i < 64 * 128; i += 512) ((float*)acc)[i] = 0.f;
    __syncthreads();

    const int hw  = tid >> 5;         // 0..15 half-wave id
    const int l32 = tid & 31;
    const int d0  = l32 * 4;

    const int s0 = offs[n0];
    const int s1 = (n0 + 64 >= N) ? E : offs[n0 + 64];
    const int total = s1 - s0;
    const int L = (total + 15) >> 4;
    int a = s0 + hw * L;
    int b = a + L; if (b > s1) b = s1;

    f32x4 r = {0.f, 0.f, 0.f, 0.f};
    int cur = -1;
    for (int s = a; s < b; ++s) {
        unsigned sd = (unsigned)srcd[s];
        int src = (int)(sd & 0xFFFFu);
        int dl  = (int)(sd >> 16);
        u16x4 ev = __builtin_nontemporal_load((const u16x4*)(eab + (size_t)s * 128 + d0));
        u16x4 xs = *(const u16x4*)(xb + (size_t)src * 128 + d0);
        if (dl != cur) {
            if (cur >= 0) {
                atomicAdd(&acc[cur][d0 + 0], r[0]);
                atomicAdd(&acc[cur][d0 + 1], r[1]);
                atomicAdd(&acc[cur][d0 + 2], r[2]);
                atomicAdd(&acc[cur][d0 + 3], r[3]);
            }
            cur = dl;
            r[0] = 0.f; r[1] = 0.f; r[2] = 0.f; r[3] = 0.f;
        }
        r[0] += fmaxf(bf2f(xs[0]) + bf2f(ev[0]), 0.f);
        r[1] += fmaxf(bf2f(xs[1]) + bf2f(ev[1]), 0.f);
        r[2] += fmaxf(bf2f(xs[2]) + bf2f(ev[2]), 0.f);
        r[3] += fmaxf(bf2f(xs[3]) + bf2f(ev[3]), 0.f);
    }
    if (cur >= 0) {
        atomicAdd(&acc[cur][d0 + 0], r[0]);
        atomicAdd(&acc[cur][d0 + 1], r[1]);
        atomicAdd(&acc[cur][d0 + 2], r[2]);
        atomicAdd(&acc[cur][d0 + 3], r[3]);
    }
    __syncthreads();

    // write-out: half-wave hw handles rows hw*4 .. hw*4+3
#pragma unroll
    for (int k = 0; k < 4; ++k) {
        int rr = hw * 4 + k;
        int n = n0 + rr;
        if (n >= N) break;
        u16x4 xv = *(const u16x4*)(xb + (size_t)n * 128 + d0);
        u16x4 o;
        o[0] = f2bf(acc[rr][d0 + 0] + bf2f(xv[0]));
        o[1] = f2bf(acc[rr][d0 + 1] + bf2f(xv[1]));
        o[2] = f2bf(acc[rr][d0 + 2] + bf2f(xv[2]));
        o[3] = f2bf(acc[rr][d0 + 3] + bf2f(xv[3]));
        *(u16x4*)(t1 + (size_t)n * 128 + d0) = o;
    }
}

// ---------------- GEMM with fused BN-affine on A (optional) + fused col stats
// out[n][c] = sum_k a[n][k]*Wt[c][k] + bias[c].  Wt is pre-converted bf16 [c][k].
// BNA=false: inp is bf16 [N][128] (pre-rounded), copied straight to LDS.
// BNA=true:  inp is f32  [N][128]; a = relu(inp*sc+sh) rounded to bf16.
// Also accumulates column sum/sumsq of out into statsOut[0..127]/[128..255].
template<bool BNA>
__global__ __launch_bounds__(256) void gemm_kernel(
    const void* __restrict__ inp,
    const unsigned short* __restrict__ Wt,  // [128][128] bf16, [c][k]
    const float* __restrict__ bias,         // [128] f32
    const float* __restrict__ statsIn,
    const float* __restrict__ gA, const float* __restrict__ bA,
    float* __restrict__ out, float* __restrict__ statsOut, int N)
{
    __shared__ __attribute__((aligned(16))) unsigned short As[64][136];   // [r][k]
    __shared__ __attribute__((aligned(16))) unsigned short Ws[128][136];  // [c][k]
    __shared__ float u0[128], u1[128];  // BNA: sc/sh during staging; then cs/cq
    const int tid = threadIdx.x;
    const int row0 = blockIdx.x * 64;

    if (BNA) {
        if (tid < 128) {
            float inv = 1.f / (float)N;
            float m = statsIn[tid] * inv;
            float v = statsIn[128 + tid] * inv - m * m;
            v = fmaxf(v, 0.f);
            float rs = rsqrtf(v + 1e-5f);
            float gr = gA[tid] * rs;
            u0[tid] = gr;
            u1[tid] = bA[tid] - m * gr;
        }
        __syncthreads();
    }

    // stage Wt -> Ws (bf16 copy, coalesced)
#pragma unroll
    for (int it = 0; it < 8; ++it) {
        int lin = (it * 256 + tid) * 8;
        int c = lin >> 7;
        int k = lin & 127;
        *(uint4*)&Ws[c][k] = *(const uint4*)(Wt + (size_t)c * 128 + k);
    }
    // stage A tile (zero-pad tail rows)
    if (BNA) {
        const float* ip = (const float*)inp;
#pragma unroll
        for (int it = 0; it < 8; ++it) {
            int lin = (it * 256 + tid) * 4;
            int r = lin >> 7;
            int c = lin & 127;
            int row = row0 + r;
            if (row < N) {
                float4 v = *(const float4*)(ip + (size_t)row * 128 + c);
                v.x = fmaxf(fmaf(v.x, u0[c + 0], u1[c + 0]), 0.f);
                v.y = fmaxf(fmaf(v.y, u0[c + 1], u1[c + 1]), 0.f);
                v.z = fmaxf(fmaf(v.z, u0[c + 2], u1[c + 2]), 0.f);
                v.w = fmaxf(fmaf(v.w, u0[c + 3], u1[c + 3]), 0.f);
                As[r][c + 0] = f2bf(v.x); As[r][c + 1] = f2bf(v.y);
                As[r][c + 2] = f2bf(v.z); As[r][c + 3] = f2bf(v.w);
            } else {
                As[r][c + 0] = 0; As[r][c + 1] = 0; As[r][c + 2] = 0; As[r][c + 3] = 0;
            }
        }
    } else {
        const unsigned short* ip = (const unsigned short*)inp;
#pragma unroll
        for (int it = 0; it < 4; ++it) {
            int lin = (it * 256 + tid) * 8;
            int r = lin >> 7;
            int c = lin & 127;
            int row = row0 + r;
            uint4 v = {0u, 0u, 0u, 0u};
            if (row < N) v = *(const uint4*)(ip + (size_t)row * 128 + c);
            *(uint4*)&As[r][c] = v;
        }
    }
    __syncthreads();
    // repurpose u0/u1 as column sum / sumsq accumulators
    if (tid < 128) { u0[tid] = 0.f; u1[tid] = 0.f; }
    __syncthreads();

    const int wave = tid >> 6;
    const int lane = tid & 63;
    const int quad = lane >> 4;
    const int m16  = lane & 15;

    // A fragments: A[m=lane&15][k=quad*8+j], 8 contiguous bf16 -> ds_read_b128
    bf16x8 af[4];
#pragma unroll
    for (int kk = 0; kk < 4; ++kk)
        af[kk] = *reinterpret_cast<const bf16x8*>(&As[wave * 16 + m16][kk * 32 + quad * 8]);

#pragma unroll
    for (int ct = 0; ct < 8; ++ct) {
        f32x4 acc = {0.f, 0.f, 0.f, 0.f};
#pragma unroll
        for (int kk = 0; kk < 4; ++kk) {
            bf16x8 bf = *reinterpret_cast<const bf16x8*>(&Ws[ct * 16 + m16][kk * 32 + quad * 8]);
            acc = __builtin_amdgcn_mfma_f32_16x16x32_bf16(af[kk], bf, acc, 0, 0, 0);
        }
        int col = ct * 16 + m16;
        float bb = bias[col];
        float s_part = 0.f, q_part = 0.f;
#pragma unroll
        for (int r = 0; r < 4; ++r) {
            int row = row0 + wave * 16 + quad * 4 + r;  // C/D: row = quad*4+reg, col = lane&15
            if (row < N) {
                float val = acc[r] + bb;
                out[(size_t)row * 128 + col] = val;
                s_part += val;
                q_part += val * val;
            }
        }
        // reduce over the 4 quad-groups that share this column (lanes ^16, ^32)
        s_part += __shfl_xor(s_part, 16); q_part += __shfl_xor(q_part, 16);
        s_part += __shfl_xor(s_part, 32); q_part += __shfl_xor(q_part, 32);
        if (lane < 16) {
            atomicAdd(&u0[col], s_part);
            atomicAdd(&u1[col], q_part);
        }
    }
    __syncthreads();
    if (tid < 128) {
        atomicAdd(&statsOut[tid],       u0[tid]);
        atomicAdd(&statsOut[128 + tid], u1[tid]);
    }
}

// out = gamma * (t - mean) * rsqrt(var + eps) + beta  (final layer, no relu)
__global__ __launch_bounds__(256) void bn_kernel(
    const float* __restrict__ t, const float* __restrict__ sum, const float* __restrict__ sq,
    const float* __restrict__ gamma, const float* __restrict__ beta,
    float* __restrict__ out, int N, int nv4)
{
    __shared__ float sc[128], sh[128];
    int tid = threadIdx.x;
    if (tid < 128) {
        float inv = 1.f / (float)N;
        float m = sum[tid] * inv;
        float v = sq[tid] * inv - m * m;
        v = fmaxf(v, 0.f);
        float rs = rsqrtf(v + 1e-5f);
        float gr = gamma[tid] * rs;
        sc[tid] = gr;
        sh[tid] = beta[tid] - m * gr;
    }
    __syncthreads();
    int g = blockIdx.x * 256 + tid;
    if (g < nv4) {
        int c = (g & 31) * 4;
        float4 v = *(const float4*)(t + (size_t)g * 4);
        float4 o;
        o.x = v.x * sc[c + 0] + sh[c + 0];
        o.y = v.y * sc[c + 1] + sh[c + 1];
        o.z = v.z * sc[c + 2] + sh[c + 2];
        o.w = v.w * sc[c + 3] + sh[c + 3];
        *(float4*)(out + (size_t)g * 4) = o;
    }
}

extern "C" void kernel_launch(void* const* d_in, const int* in_sizes, int n_in,
                              void* d_out, int out_size, void* d_ws, size_t ws_size,
                              hipStream_t stream)
{
    const float* x  = (const float*)d_in[0];
    const int* ei   = (const int*)d_in[1];
    const float* ea = (const float*)d_in[2];
    // d_in[3] = batch (unused)
    const float* W1 = (const float*)d_in[4];
    const float* b1 = (const float*)d_in[5];
    const float* gm = (const float*)d_in[6];
    const float* bm = (const float*)d_in[7];
    const float* W2 = (const float*)d_in[8];
    const float* b2 = (const float*)d_in[9];
    const float* go = (const float*)d_in[10];
    const float* bo = (const float*)d_in[11];
    float* out = (float*)d_out;

    const int N = in_sizes[0] / 128;   // 50000
    const int E = in_sizes[2] / 128;   // 800000

    char* w = (char*)d_ws;
    float* t2   = (float*)w;            w += (size_t)N * 128 * 4;   // gemm1 out (pre-BN1)
    float* t3   = (float*)w;            w += (size_t)N * 128 * 4;   // gemm2 out (pre-BN2)
    unsigned short* t1 = (unsigned short*)w; w += (size_t)N * 128 * 2;  // agg out, bf16
    unsigned short* xb = (unsigned short*)w; w += (size_t)N * 128 * 2;  // agg in, bf16
    unsigned short* Wt = (unsigned short*)w; w += (size_t)6 * 16384 * 2; // W bf16 [c][k]
    float* stats = (float*)w;           w += 1536 * 4;              // 6 x (sum[128], sq[128])
    int* i64flag = (int*)w;             w += 16;
    int* counts  = (int*)w;             w += (size_t)N * 4;
    int* offs    = (int*)w;             w += (size_t)N * 4;
    int* cursor  = (int*)w;             w += (size_t)N * 4;
    int* bsum    = (int*)w;             w += 256 * 4;
    int* srcd    = (int*)w;             w += (size_t)E * 4;         // slot -> src | dl<<16
    int* eslot   = (int*)w;             w += (size_t)E * 4;         // edge -> slot
    unsigned short* eab = (unsigned short*)w; w += (size_t)E * 128 * 2;  // ea bf16, CSR order

    const int nv4 = N * 32;
    const int gElem = (nv4 + 255) / 256;
    const int gGemm = (N + 63) / 64;
    const int gEdge = (E + 255) / 256;
    const int nb    = (N + 255) / 256;
    const int gAgg  = (N + 63) / 64;
    const int gConv = (N * 16 + 255) / 256;            // x->xb, xbn
    const int gEa   = (E * 16 + 255) / 256;

    // ---- CSR build + W/x/ea pre-convert (all layer-invariant) ----
    setup_kernel<<<gConv, 256, 0, stream>>>(ei, i64flag, counts, stats, W1, W2, Wt, x, xb, N);
    hist_kernel<<<gEdge, 256, 0, stream>>>(ei, i64flag, counts, E);
    scan1_kernel<<<nb, 256, 0, stream>>>(counts, offs, bsum, N);
    scan2_kernel<<<1, 256, 0, stream>>>(bsum, nb);
    scan3_kernel<<<nb, 256, 0, stream>>>(offs, bsum, cursor, N);
    scatter_kernel<<<gEdge, 256, 0, stream>>>(ei, i64flag, cursor, srcd, eslot, E);
    eaconv_kernel<<<gEa, 256, 0, stream>>>(ea, eslot, eab, E);

    for (int i = 0; i < 3; ++i) {
        float* sMlp = stats + (size_t)i * 512;        // gemm1 output stats
        float* sOut = stats + (size_t)i * 512 + 256;  // gemm2 output stats

        if (i > 0) {
            float* sPrev = stats + (size_t)(i - 1) * 512 + 256;
            xbn_kernel<<<gConv, 256, 0, stream>>>(
                t3, sPrev, sPrev + 128, go + (i - 1) * 128, bo + (i - 1) * 128, xb, N);
        }
        agg_kernel<<<gAgg, 512, 0, stream>>>(xb, eab, srcd, offs, t1, N, E);
        gemm_kernel<false><<<gGemm, 256, 0, stream>>>(
            t1, Wt + (size_t)i * 16384, b1 + i * 128,
            nullptr, nullptr, nullptr, t2, sMlp, N);
        gemm_kernel<true><<<gGemm, 256, 0, stream>>>(
            t2, Wt + (size_t)(i + 3) * 16384, b2 + i * 128,
            sMlp, gm + i * 128, bm + i * 128, t3, sOut, N);
    }
    // final outer BN (no relu) -> out
    bn_kernel<<<gElem, 256, 0, stream>>>(t3, stats + 2 * 512 + 256, stats + 2 * 512 + 384,
                                         go + 256, bo + 256, out, N, nv4);
}

// Round 9
// 1150.230 us; speedup vs baseline: 1.1225x; 1.1225x over previous
//
#include <hip/hip_runtime.h>

#define DEV __device__ __forceinline__

typedef __bf16 bf16x8 __attribute__((ext_vector_type(8)));
typedef float f32x4 __attribute__((ext_vector_type(4)));

DEV unsigned short f2bf(float f) {
    unsigned u = __builtin_bit_cast(unsigned, f);
    u += 0x7fffu + ((u >> 16) & 1u);   // round-to-nearest-even
    return (unsigned short)(u >> 16);
}

// zero counts[N] + stats[1536]; pre-convert W1,W2 (6 mats) to bf16 [c][k];
// block 0 detects int64-vs-int32 edge_index layout.
__global__ __launch_bounds__(256) void setup_kernel(
    const int* __restrict__ ei, int* __restrict__ flag,
    int* __restrict__ counts, float* __restrict__ stats,
    const float* __restrict__ W1, const float* __restrict__ W2,
    unsigned short* __restrict__ Wt, int N)
{
    int g = blockIdx.x * 256 + threadIdx.x;
    if (g < N) counts[g] = 0;
    if (g < 1536) stats[g] = 0.f;
    if (g < 12288) {                       // 6 mats x 16 k-groups x 128 cols
        int mat = g >> 11;
        int r = g & 2047;
        int c = r & 127;
        int kg = (r >> 7) * 8;
        const float* Wsrc = (mat < 3) ? (W1 + (size_t)mat * 16384)
                                      : (W2 + (size_t)(mat - 3) * 16384);
        unsigned short o[8];
#pragma unroll
        for (int q = 0; q < 8; ++q)
            o[q] = f2bf(Wsrc[(size_t)(kg + q) * 128 + c]);
        *(uint4*)(Wt + ((size_t)mat * 128 + c) * 128 + kg) = *(const uint4*)o;
    }
    if (blockIdx.x == 0 && threadIdx.x < 64) {
        int t = threadIdx.x;
        int v = (t < 32) ? ei[2 * t + 1] : 0;
        unsigned long long b = __ballot(v == 0);
        if (t == 0) *flag = (b == ~0ull) ? 1 : 0;
    }
}

__global__ __launch_bounds__(256) void hist_kernel(
    const int* __restrict__ ei, const int* __restrict__ i64flag,
    int* __restrict__ counts, int E)
{
    int e = blockIdx.x * 256 + threadIdx.x;
    if (e >= E) return;
    int d = (*i64flag) ? ei[2 * (size_t)E + 2 * (size_t)e] : ei[(size_t)E + e];
    atomicAdd(&counts[d], 1);
}

// block-level inclusive scan; writes per-element exclusive offsets + block totals
__global__ __launch_bounds__(256) void scan1_kernel(
    const int* __restrict__ counts, int* __restrict__ offs,
    int* __restrict__ bsum, int N)
{
    __shared__ int s[256];
    int tid = threadIdx.x;
    int i = blockIdx.x * 256 + tid;
    int c = (i < N) ? counts[i] : 0;
    s[tid] = c;
    __syncthreads();
#pragma unroll
    for (int off = 1; off < 256; off <<= 1) {
        int add = (tid >= off) ? s[tid - off] : 0;
        __syncthreads();
        s[tid] += add;
        __syncthreads();
    }
    int incl = s[tid];
    if (i < N) offs[i] = incl - c;            // exclusive within block
    if (tid == 255) bsum[blockIdx.x] = incl;  // block total
}

// merged scan2+scan3: every block re-scans the (<=256) block sums in LDS,
// adds its prefix to offs, fills cursor, and block 0 writes offs[N] = E.
__global__ __launch_bounds__(256) void scan23_kernel(
    int* __restrict__ offs, const int* __restrict__ bsum,
    int* __restrict__ cursor, int N, int E, int nb)
{
    __shared__ int s[256];
    int tid = threadIdx.x;
    int v = (tid < nb) ? bsum[tid] : 0;
    s[tid] = v;
    __syncthreads();
#pragma unroll
    for (int off = 1; off < 256; off <<= 1) {
        int add = (tid >= off) ? s[tid - off] : 0;
        __syncthreads();
        s[tid] += add;
        __syncthreads();
    }
    int pre = (blockIdx.x == 0) ? 0 : s[blockIdx.x - 1];
    int i = blockIdx.x * 256 + tid;
    if (i < N) {
        int o = offs[i] + pre;
        offs[i] = o;
        cursor[i] = o;
    }
    if (blockIdx.x == 0 && tid == 0) offs[N] = E;
}

// CSR scatter: el[slot] = (src, edge_id)
__global__ __launch_bounds__(256) void scatter_kernel(
    const int* __restrict__ ei, const int* __restrict__ i64flag,
    int* __restrict__ cursor, int2* __restrict__ el, int E)
{
    int e = blockIdx.x * 256 + threadIdx.x;
    if (e >= E) return;
    int s, d;
    if (*i64flag) {
        s = ei[2 * (size_t)e];
        d = ei[2 * (size_t)E + 2 * (size_t)e];
    } else {
        s = ei[e];
        d = ei[(size_t)E + e];
    }
    int pos = atomicAdd(&cursor[d], 1);
    el[pos] = make_int2(s, e);
}

// ---------------- aggregation ----------------
// t1[n] (bf16) = xbn[n] + sum_{slot in CSR[n]} relu(xbn[el[slot].x] + ea[el[slot].y])
// xbn = AFFINE ? relu(x*sc + sh) : x  (outer BN+ReLU of previous layer folded in).
// One wave per node; half-wave 0 takes the first ceil(deg/2) CSR slots, half 1
// the rest. 4-edge unroll keeps 8 gathers in flight per half-wave.
// Degree comes from adjacent offs entries (offs has N+1 entries).
template<bool AFFINE>
__global__ __launch_bounds__(512) void agg_kernel(
    const float* __restrict__ x, const float* __restrict__ ea,
    const int2* __restrict__ el, const int* __restrict__ offs,
    const float* __restrict__ statsIn, const float* __restrict__ gamma,
    const float* __restrict__ beta,
    unsigned short* __restrict__ t1, int N)
{
    __shared__ float sc[128], sh[128];
    int tid = threadIdx.x;
    if (AFFINE) {
        if (tid < 128) {
            float inv = 1.f / (float)N;
            float m = statsIn[tid] * inv;
            float v = statsIn[128 + tid] * inv - m * m;
            v = fmaxf(v, 0.f);
            float rs = rsqrtf(v + 1e-5f);
            float gr = gamma[tid] * rs;
            sc[tid] = gr;
            sh[tid] = beta[tid] - m * gr;
        }
        __syncthreads();
    }

    const int lane = tid & 63;
    const int half = lane >> 5;
    const int l32  = lane & 31;
    const int d0   = l32 * 4;

    f32x4 scv = {1.f, 1.f, 1.f, 1.f}, shv = {0.f, 0.f, 0.f, 0.f};
    if (AFFINE) {
        scv = *(const f32x4*)(sc + d0);
        shv = *(const f32x4*)(sh + d0);
    }

    const int n = blockIdx.x * 8 + (tid >> 6);
    if (n >= N) return;

    const int start = offs[n];
    const int deg   = offs[n + 1] - start;
    const int mid = (deg + 1) >> 1;
    int j        = half ? mid : 0;
    const int hi = half ? deg : mid;

    f32x4 acc = {0.f, 0.f, 0.f, 0.f};
    if (half == 0) {
        f32x4 cv = *(const f32x4*)(x + (size_t)n * 128 + d0);
        if (AFFINE) {
#pragma unroll
            for (int q = 0; q < 4; ++q)
                cv[q] = fmaxf(fmaf(cv[q], scv[q], shv[q]), 0.f);
        }
        acc = cv;
    }

#define APPLY(GX, AV) { \
    if (AFFINE) { \
        _Pragma("unroll") \
        for (int q = 0; q < 4; ++q) (GX)[q] = fmaxf(fmaf((GX)[q], scv[q], shv[q]), 0.f); \
    } \
    _Pragma("unroll") \
    for (int q = 0; q < 4; ++q) acc[q] += fmaxf((GX)[q] + (AV)[q], 0.f); }

    for (; j + 3 < hi; j += 4) {
        int2 e0 = el[start + j + 0];
        int2 e1 = el[start + j + 1];
        int2 e2 = el[start + j + 2];
        int2 e3 = el[start + j + 3];
        f32x4 x0 = *(const f32x4*)(x + (size_t)e0.x * 128 + d0);
        f32x4 x1 = *(const f32x4*)(x + (size_t)e1.x * 128 + d0);
        f32x4 x2 = *(const f32x4*)(x + (size_t)e2.x * 128 + d0);
        f32x4 x3 = *(const f32x4*)(x + (size_t)e3.x * 128 + d0);
        f32x4 a0 = __builtin_nontemporal_load((const f32x4*)(ea + (size_t)e0.y * 128 + d0));
        f32x4 a1 = __builtin_nontemporal_load((const f32x4*)(ea + (size_t)e1.y * 128 + d0));
        f32x4 a2 = __builtin_nontemporal_load((const f32x4*)(ea + (size_t)e2.y * 128 + d0));
        f32x4 a3 = __builtin_nontemporal_load((const f32x4*)(ea + (size_t)e3.y * 128 + d0));
        APPLY(x0, a0); APPLY(x1, a1); APPLY(x2, a2); APPLY(x3, a3);
    }
    for (; j < hi; ++j) {
        int2 e0 = el[start + j];
        f32x4 x0 = *(const f32x4*)(x + (size_t)e0.x * 128 + d0);
        f32x4 a0 = __builtin_nontemporal_load((const f32x4*)(ea + (size_t)e0.y * 128 + d0));
        APPLY(x0, a0);
    }
#undef APPLY

    // combine the two half-wave partial sums
#pragma unroll
    for (int q = 0; q < 4; ++q) acc[q] += __shfl_xor(acc[q], 32);

    if (half == 0) {
        ushort4 o;
        o.x = f2bf(acc[0]); o.y = f2bf(acc[1]);
        o.z = f2bf(acc[2]); o.w = f2bf(acc[3]);
        *(ushort4*)(t1 + (size_t)n * 128 + d0) = o;
    }
}

// ---------------- GEMM with fused BN-affine on A (optional) + fused col stats
// out[n][c] = sum_k a[n][k]*Wt[c][k] + bias[c].  Wt is pre-converted bf16 [c][k].
// BNA=false: inp is bf16 [N][128] (pre-rounded), copied straight to LDS.
// BNA=true:  inp is f32  [N][128]; a = relu(inp*sc+sh) rounded to bf16.
// Also accumulates column sum/sumsq of out into statsOut[0..127]/[128..255].
template<bool BNA>
__global__ __launch_bounds__(256) void gemm_kernel(
    const void* __restrict__ inp,
    const unsigned short* __restrict__ Wt,  // [128][128] bf16, [c][k]
    const float* __restrict__ bias,         // [128] f32
    const float* __restrict__ statsIn,
    const float* __restrict__ gA, const float* __restrict__ bA,
    float* __restrict__ out, float* __restrict__ statsOut, int N)
{
    __shared__ __attribute__((aligned(16))) unsigned short As[64][136];   // [r][k]
    __shared__ __attribute__((aligned(16))) unsigned short Ws[128][136];  // [c][k]
    __shared__ float u0[128], u1[128];  // BNA: sc/sh during staging; then cs/cq
    const int tid = threadIdx.x;
    const int row0 = blockIdx.x * 64;

    if (BNA) {
        if (tid < 128) {
            float inv = 1.f / (float)N;
            float m = statsIn[tid] * inv;
            float v = statsIn[128 + tid] * inv - m * m;
            v = fmaxf(v, 0.f);
            float rs = rsqrtf(v + 1e-5f);
            float gr = gA[tid] * rs;
            u0[tid] = gr;
            u1[tid] = bA[tid] - m * gr;
        }
        __syncthreads();
    }

    // stage Wt -> Ws (bf16 copy, coalesced)
#pragma unroll
    for (int it = 0; it < 8; ++it) {
        int lin = (it * 256 + tid) * 8;
        int c = lin >> 7;
        int k = lin & 127;
        *(uint4*)&Ws[c][k] = *(const uint4*)(Wt + (size_t)c * 128 + k);
    }
    // stage A tile (zero-pad tail rows)
    if (BNA) {
        const float* ip = (const float*)inp;
#pragma unroll
        for (int it = 0; it < 8; ++it) {
            int lin = (it * 256 + tid) * 4;
            int r = lin >> 7;
            int c = lin & 127;
            int row = row0 + r;
            if (row < N) {
                float4 v = *(const float4*)(ip + (size_t)row * 128 + c);
                v.x = fmaxf(fmaf(v.x, u0[c + 0], u1[c + 0]), 0.f);
                v.y = fmaxf(fmaf(v.y, u0[c + 1], u1[c + 1]), 0.f);
                v.z = fmaxf(fmaf(v.z, u0[c + 2], u1[c + 2]), 0.f);
                v.w = fmaxf(fmaf(v.w, u0[c + 3], u1[c + 3]), 0.f);
                As[r][c + 0] = f2bf(v.x); As[r][c + 1] = f2bf(v.y);
                As[r][c + 2] = f2bf(v.z); As[r][c + 3] = f2bf(v.w);
            } else {
                As[r][c + 0] = 0; As[r][c + 1] = 0; As[r][c + 2] = 0; As[r][c + 3] = 0;
            }
        }
    } else {
        const unsigned short* ip = (const unsigned short*)inp;
#pragma unroll
        for (int it = 0; it < 4; ++it) {
            int lin = (it * 256 + tid) * 8;
            int r = lin >> 7;
            int c = lin & 127;
            int row = row0 + r;
            uint4 v = {0u, 0u, 0u, 0u};
            if (row < N) v = *(const uint4*)(ip + (size_t)row * 128 + c);
            *(uint4*)&As[r][c] = v;
        }
    }
    __syncthreads();
    // repurpose u0/u1 as column sum / sumsq accumulators
    if (tid < 128) { u0[tid] = 0.f; u1[tid] = 0.f; }
    __syncthreads();

    const int wave = tid >> 6;
    const int lane = tid & 63;
    const int quad = lane >> 4;
    const int m16  = lane & 15;

    // A fragments: A[m=lane&15][k=quad*8+j], 8 contiguous bf16 -> ds_read_b128
    bf16x8 af[4];
#pragma unroll
    for (int kk = 0; kk < 4; ++kk)
        af[kk] = *reinterpret_cast<const bf16x8*>(&As[wave * 16 + m16][kk * 32 + quad * 8]);

#pragma unroll
    for (int ct = 0; ct < 8; ++ct) {
        f32x4 acc = {0.f, 0.f, 0.f, 0.f};
#pragma unroll
        for (int kk = 0; kk < 4; ++kk) {
            bf16x8 bf = *reinterpret_cast<const bf16x8*>(&Ws[ct * 16 + m16][kk * 32 + quad * 8]);
            acc = __builtin_amdgcn_mfma_f32_16x16x32_bf16(af[kk], bf, acc, 0, 0, 0);
        }
        int col = ct * 16 + m16;
        float bb = bias[col];
        float s_part = 0.f, q_part = 0.f;
#pragma unroll
        for (int r = 0; r < 4; ++r) {
            int row = row0 + wave * 16 + quad * 4 + r;  // C/D: row = quad*4+reg, col = lane&15
            if (row < N) {
                float val = acc[r] + bb;
                out[(size_t)row * 128 + col] = val;
                s_part += val;
                q_part += val * val;
            }
        }
        // reduce over the 4 quad-groups that share this column (lanes ^16, ^32)
        s_part += __shfl_xor(s_part, 16); q_part += __shfl_xor(q_part, 16);
        s_part += __shfl_xor(s_part, 32); q_part += __shfl_xor(q_part, 32);
        if (lane < 16) {
            atomicAdd(&u0[col], s_part);
            atomicAdd(&u1[col], q_part);
        }
    }
    __syncthreads();
    if (tid < 128) {
        atomicAdd(&statsOut[tid],       u0[tid]);
        atomicAdd(&statsOut[128 + tid], u1[tid]);
    }
}

// out = gamma * (t - mean) * rsqrt(var + eps) + beta  (final layer, no relu)
__global__ __launch_bounds__(256) void bn_kernel(
    const float* __restrict__ t, const float* __restrict__ sum, const float* __restrict__ sq,
    const float* __restrict__ gamma, const float* __restrict__ beta,
    float* __restrict__ out, int N, int nv4)
{
    __shared__ float sc[128], sh[128];
    int tid = threadIdx.x;
    if (tid < 128) {
        float inv = 1.f / (float)N;
        float m = sum[tid] * inv;
        float v = sq[tid] * inv - m * m;
        v = fmaxf(v, 0.f);
        float rs = rsqrtf(v + 1e-5f);
        float gr = gamma[tid] * rs;
        sc[tid] = gr;
        sh[tid] = beta[tid] - m * gr;
    }
    __syncthreads();
    int g = blockIdx.x * 256 + tid;
    if (g < nv4) {
        int c = (g & 31) * 4;
        float4 v = *(const float4*)(t + (size_t)g * 4);
        float4 o;
        o.x = v.x * sc[c + 0] + sh[c + 0];
        o.y = v.y * sc[c + 1] + sh[c + 1];
        o.z = v.z * sc[c + 2] + sh[c + 2];
        o.w = v.w * sc[c + 3] + sh[c + 3];
        *(float4*)(out + (size_t)g * 4) = o;
    }
}

extern "C" void kernel_launch(void* const* d_in, const int* in_sizes, int n_in,
                              void* d_out, int out_size, void* d_ws, size_t ws_size,
                              hipStream_t stream)
{
    const float* x  = (const float*)d_in[0];
    const int* ei   = (const int*)d_in[1];
    const float* ea = (const float*)d_in[2];
    // d_in[3] = batch (unused)
    const float* W1 = (const float*)d_in[4];
    const float* b1 = (const float*)d_in[5];
    const float* gm = (const float*)d_in[6];
    const float* bm = (const float*)d_in[7];
    const float* W2 = (const float*)d_in[8];
    const float* b2 = (const float*)d_in[9];
    const float* go = (const float*)d_in[10];
    const float* bo = (const float*)d_in[11];
    float* out = (float*)d_out;

    const int N = in_sizes[0] / 128;   // 50000
    const int E = in_sizes[2] / 128;   // 800000

    char* w = (char*)d_ws;
    float* t2   = (float*)w;            w += (size_t)N * 128 * 4;   // gemm1 out (pre-BN1)
    float* t3   = (float*)w;            w += (size_t)N * 128 * 4;   // gemm2 out (pre-BN2)
    unsigned short* t1 = (unsigned short*)w; w += (size_t)N * 128 * 2;  // agg out, bf16
    unsigned short* Wt = (unsigned short*)w; w += (size_t)6 * 16384 * 2; // W bf16 [c][k]
    float* stats = (float*)w;           w += 1536 * 4;              // 6 x (sum[128], sq[128])
    int* i64flag = (int*)w;             w += 16;
    int* counts  = (int*)w;             w += (size_t)N * 4;
    int* offs    = (int*)w;             w += (size_t)(N + 16) * 4;  // N+1 entries
    int* cursor  = (int*)w;             w += (size_t)N * 4;
    int* bsum    = (int*)w;             w += 256 * 4;
    int2* el     = (int2*)w;            w += (size_t)E * 8;         // CSR: (src, edge)

    const int nv4 = N * 32;
    const int gElem = (nv4 + 255) / 256;
    const int gGemm = (N + 63) / 64;
    const int gEdge = (E + 255) / 256;
    const int nb    = (N + 255) / 256;
    const int gAgg  = (N + 7) / 8;
    const int gSetup = 12288 / 256 > nb ? 12288 / 256 : nb;

    // ---- CSR build + W pre-convert (both layer-invariant) ----
    setup_kernel<<<gSetup, 256, 0, stream>>>(ei, i64flag, counts, stats, W1, W2, Wt, N);
    hist_kernel<<<gEdge, 256, 0, stream>>>(ei, i64flag, counts, E);
    scan1_kernel<<<nb, 256, 0, stream>>>(counts, offs, bsum, N);
    scan23_kernel<<<nb, 256, 0, stream>>>(offs, bsum, cursor, N, E, nb);
    scatter_kernel<<<gEdge, 256, 0, stream>>>(ei, i64flag, cursor, el, E);

    for (int i = 0; i < 3; ++i) {
        float* sMlp = stats + (size_t)i * 512;        // gemm1 output stats
        float* sOut = stats + (size_t)i * 512 + 256;  // gemm2 output stats

        if (i == 0) {
            agg_kernel<false><<<gAgg, 512, 0, stream>>>(
                x, ea, el, offs, nullptr, nullptr, nullptr, t1, N);
        } else {
            float* sPrev = stats + (size_t)(i - 1) * 512 + 256;
            agg_kernel<true><<<gAgg, 512, 0, stream>>>(
                t3, ea, el, offs, sPrev, go + (i - 1) * 128, bo + (i - 1) * 128, t1, N);
        }
        gemm_kernel<false><<<gGemm, 256, 0, stream>>>(
            t1, Wt + (size_t)i * 16384, b1 + i * 128,
            nullptr, nullptr, nullptr, t2, sMlp, N);
        gemm_kernel<true><<<gGemm, 256, 0, stream>>>(
            t2, Wt + (size_t)(i + 3) * 16384, b2 + i * 128,
            sMlp, gm + i * 128, bm + i * 128, t3, sOut, N);
    }
    // final outer BN (no relu) -> out
    bn_kernel<<<gElem, 256, 0, stream>>>(t3, stats + 2 * 512 + 256, stats + 2 * 512 + 384,
                                         go + 256, bo + 256, out, N, nv4);
}

// Round 10
// 1065.699 us; speedup vs baseline: 1.2116x; 1.0793x over previous
//
#include <hip/hip_runtime.h>

#define DEV __device__ __forceinline__

typedef __bf16 bf16x8 __attribute__((ext_vector_type(8)));
typedef float f32x4 __attribute__((ext_vector_type(4)));

DEV unsigned short f2bf(float f) {
    unsigned u = __builtin_bit_cast(unsigned, f);
    u += 0x7fffu + ((u >> 16) & 1u);   // round-to-nearest-even
    return (unsigned short)(u >> 16);
}

DEV float bf2f(unsigned short h) {
    unsigned u = (unsigned)h << 16;
    return __builtin_bit_cast(float, u);
}

// zero counts[N] + stats[1536]; pre-convert W1,W2 (6 mats) to bf16 [c][k];
// block 0 detects int64-vs-int32 edge_index layout.
__global__ __launch_bounds__(256) void setup_kernel(
    const int* __restrict__ ei, int* __restrict__ flag,
    int* __restrict__ counts, float* __restrict__ stats,
    const float* __restrict__ W1, const float* __restrict__ W2,
    unsigned short* __restrict__ Wt, int N)
{
    int g = blockIdx.x * 256 + threadIdx.x;
    if (g < N) counts[g] = 0;
    if (g < 1536) stats[g] = 0.f;
    if (g < 12288) {                       // 6 mats x 16 k-groups x 128 cols
        int mat = g >> 11;
        int r = g & 2047;
        int c = r & 127;
        int kg = (r >> 7) * 8;
        const float* Wsrc = (mat < 3) ? (W1 + (size_t)mat * 16384)
                                      : (W2 + (size_t)(mat - 3) * 16384);
        unsigned short o[8];
#pragma unroll
        for (int q = 0; q < 8; ++q)
            o[q] = f2bf(Wsrc[(size_t)(kg + q) * 128 + c]);
        *(uint4*)(Wt + ((size_t)mat * 128 + c) * 128 + kg) = *(const uint4*)o;
    }
    if (blockIdx.x == 0 && threadIdx.x < 64) {
        int t = threadIdx.x;
        int v = (t < 32) ? ei[2 * t + 1] : 0;
        unsigned long long b = __ballot(v == 0);
        if (t == 0) *flag = (b == ~0ull) ? 1 : 0;
    }
}

__global__ __launch_bounds__(256) void hist_kernel(
    const int* __restrict__ ei, const int* __restrict__ i64flag,
    int* __restrict__ counts, int E)
{
    int e = blockIdx.x * 256 + threadIdx.x;
    if (e >= E) return;
    int d = (*i64flag) ? ei[2 * (size_t)E + 2 * (size_t)e] : ei[(size_t)E + e];
    atomicAdd(&counts[d], 1);
}

// block-level inclusive scan; writes per-element exclusive offsets + block totals
__global__ __launch_bounds__(256) void scan1_kernel(
    const int* __restrict__ counts, int* __restrict__ offs,
    int* __restrict__ bsum, int N)
{
    __shared__ int s[256];
    int tid = threadIdx.x;
    int i = blockIdx.x * 256 + tid;
    int c = (i < N) ? counts[i] : 0;
    s[tid] = c;
    __syncthreads();
#pragma unroll
    for (int off = 1; off < 256; off <<= 1) {
        int add = (tid >= off) ? s[tid - off] : 0;
        __syncthreads();
        s[tid] += add;
        __syncthreads();
    }
    int incl = s[tid];
    if (i < N) offs[i] = incl - c;            // exclusive within block
    if (tid == 255) bsum[blockIdx.x] = incl;  // block total
}

// merged scan2+scan3: every block re-scans the (<=256) block sums in LDS,
// adds its prefix to offs, fills cursor, and block 0 writes offs[N] = E.
__global__ __launch_bounds__(256) void scan23_kernel(
    int* __restrict__ offs, const int* __restrict__ bsum,
    int* __restrict__ cursor, int N, int E, int nb)
{
    __shared__ int s[256];
    int tid = threadIdx.x;
    int v = (tid < nb) ? bsum[tid] : 0;
    s[tid] = v;
    __syncthreads();
#pragma unroll
    for (int off = 1; off < 256; off <<= 1) {
        int add = (tid >= off) ? s[tid - off] : 0;
        __syncthreads();
        s[tid] += add;
        __syncthreads();
    }
    int pre = (blockIdx.x == 0) ? 0 : s[blockIdx.x - 1];
    int i = blockIdx.x * 256 + tid;
    if (i < N) {
        int o = offs[i] + pre;
        offs[i] = o;
        cursor[i] = o;
    }
    if (blockIdx.x == 0 && tid == 0) offs[N] = E;
}

// CSR scatter: el[slot] = (src, edge_id)
__global__ __launch_bounds__(256) void scatter_kernel(
    const int* __restrict__ ei, const int* __restrict__ i64flag,
    int* __restrict__ cursor, int2* __restrict__ el, int E)
{
    int e = blockIdx.x * 256 + threadIdx.x;
    if (e >= E) return;
    int s, d;
    if (*i64flag) {
        s = ei[2 * (size_t)e];
        d = ei[2 * (size_t)E + 2 * (size_t)e];
    } else {
        s = ei[e];
        d = ei[(size_t)E + e];
    }
    int pos = atomicAdd(&cursor[d], 1);
    el[pos] = make_int2(s, e);
}

// ---------------- aggregation ----------------
// t1[n] (bf16) = xbn[n] + sum_{slot in CSR[n]} relu(xbn[el[slot].x] + ea[el[slot].y])
// xbn = AFFINE ? relu(x*sc + sh) : x  (outer BN+ReLU of previous layer folded in).
// One wave per node; half-wave 0 takes the first ceil(deg/2) CSR slots, half 1
// the rest. 4-edge unroll keeps 8 gathers in flight per half-wave.
template<bool AFFINE>
__global__ __launch_bounds__(512) void agg_kernel(
    const float* __restrict__ x, const float* __restrict__ ea,
    const int2* __restrict__ el, const int* __restrict__ offs,
    const float* __restrict__ statsIn, const float* __restrict__ gamma,
    const float* __restrict__ beta,
    unsigned short* __restrict__ t1, int N)
{
    __shared__ float sc[128], sh[128];
    int tid = threadIdx.x;
    if (AFFINE) {
        if (tid < 128) {
            float inv = 1.f / (float)N;
            float m = statsIn[tid] * inv;
            float v = statsIn[128 + tid] * inv - m * m;
            v = fmaxf(v, 0.f);
            float rs = rsqrtf(v + 1e-5f);
            float gr = gamma[tid] * rs;
            sc[tid] = gr;
            sh[tid] = beta[tid] - m * gr;
        }
        __syncthreads();
    }

    const int lane = tid & 63;
    const int half = lane >> 5;
    const int l32  = lane & 31;
    const int d0   = l32 * 4;

    f32x4 scv = {1.f, 1.f, 1.f, 1.f}, shv = {0.f, 0.f, 0.f, 0.f};
    if (AFFINE) {
        scv = *(const f32x4*)(sc + d0);
        shv = *(const f32x4*)(sh + d0);
    }

    const int n = blockIdx.x * 8 + (tid >> 6);
    if (n >= N) return;

    const int start = offs[n];
    const int deg   = offs[n + 1] - start;
    const int mid = (deg + 1) >> 1;
    int j        = half ? mid : 0;
    const int hi = half ? deg : mid;

    f32x4 acc = {0.f, 0.f, 0.f, 0.f};
    if (half == 0) {
        f32x4 cv = *(const f32x4*)(x + (size_t)n * 128 + d0);
        if (AFFINE) {
#pragma unroll
            for (int q = 0; q < 4; ++q)
                cv[q] = fmaxf(fmaf(cv[q], scv[q], shv[q]), 0.f);
        }
        acc = cv;
    }

#define APPLY(GX, AV) { \
    if (AFFINE) { \
        _Pragma("unroll") \
        for (int q = 0; q < 4; ++q) (GX)[q] = fmaxf(fmaf((GX)[q], scv[q], shv[q]), 0.f); \
    } \
    _Pragma("unroll") \
    for (int q = 0; q < 4; ++q) acc[q] += fmaxf((GX)[q] + (AV)[q], 0.f); }

    for (; j + 3 < hi; j += 4) {
        int2 e0 = el[start + j + 0];
        int2 e1 = el[start + j + 1];
        int2 e2 = el[start + j + 2];
        int2 e3 = el[start + j + 3];
        f32x4 x0 = *(const f32x4*)(x + (size_t)e0.x * 128 + d0);
        f32x4 x1 = *(const f32x4*)(x + (size_t)e1.x * 128 + d0);
        f32x4 x2 = *(const f32x4*)(x + (size_t)e2.x * 128 + d0);
        f32x4 x3 = *(const f32x4*)(x + (size_t)e3.x * 128 + d0);
        f32x4 a0 = __builtin_nontemporal_load((const f32x4*)(ea + (size_t)e0.y * 128 + d0));
        f32x4 a1 = __builtin_nontemporal_load((const f32x4*)(ea + (size_t)e1.y * 128 + d0));
        f32x4 a2 = __builtin_nontemporal_load((const f32x4*)(ea + (size_t)e2.y * 128 + d0));
        f32x4 a3 = __builtin_nontemporal_load((const f32x4*)(ea + (size_t)e3.y * 128 + d0));
        APPLY(x0, a0); APPLY(x1, a1); APPLY(x2, a2); APPLY(x3, a3);
    }
    for (; j < hi; ++j) {
        int2 e0 = el[start + j];
        f32x4 x0 = *(const f32x4*)(x + (size_t)e0.x * 128 + d0);
        f32x4 a0 = __builtin_nontemporal_load((const f32x4*)(ea + (size_t)e0.y * 128 + d0));
        APPLY(x0, a0);
    }
#undef APPLY

    // combine the two half-wave partial sums
#pragma unroll
    for (int q = 0; q < 4; ++q) acc[q] += __shfl_xor(acc[q], 32);

    if (half == 0) {
        ushort4 o;
        o.x = f2bf(acc[0]); o.y = f2bf(acc[1]);
        o.z = f2bf(acc[2]); o.w = f2bf(acc[3]);
        *(ushort4*)(t1 + (size_t)n * 128 + d0) = o;
    }
}

// ---------------- GEMM 128x128 tile, fused BN-affine on A + fused col stats
// out[n][c] = sum_k a[n][k]*Wt[c][k] + bias[c].  Wt is bf16 [c][k]; inp is bf16.
// BNA: a = bf16(relu(inp*sc+sh)); else a = inp.
// OUTBF: out stored bf16, else f32. Stats accumulate on pre-round f32 values.
template<bool BNA, bool OUTBF>
__global__ __launch_bounds__(256) void gemm_kernel(
    const unsigned short* __restrict__ inp,   // [N][128] bf16
    const unsigned short* __restrict__ Wt,    // [128][128] bf16, [c][k]
    const float* __restrict__ bias,           // [128] f32
    const float* __restrict__ statsIn,
    const float* __restrict__ gA, const float* __restrict__ bA,
    void* __restrict__ outv, float* __restrict__ statsOut, int N)
{
    __shared__ __attribute__((aligned(16))) unsigned short As[128][136];  // [r][k]
    __shared__ __attribute__((aligned(16))) unsigned short Ws[128][136];  // [c][k]
    __shared__ float u0[128], u1[128];  // BNA: sc/sh during staging; then stats
    const int tid = threadIdx.x;
    const int row0 = blockIdx.x * 128;

    if (BNA) {
        if (tid < 128) {
            float inv = 1.f / (float)N;
            float m = statsIn[tid] * inv;
            float v = statsIn[128 + tid] * inv - m * m;
            v = fmaxf(v, 0.f);
            float rs = rsqrtf(v + 1e-5f);
            float gr = gA[tid] * rs;
            u0[tid] = gr;
            u1[tid] = bA[tid] - m * gr;
        }
        __syncthreads();
    }

    // stage Wt -> Ws (bf16 copy, coalesced): 16384 elems, 8 iters
#pragma unroll
    for (int it = 0; it < 8; ++it) {
        int lin = (it * 256 + tid) * 8;
        int c = lin >> 7;
        int k = lin & 127;
        *(uint4*)&Ws[c][k] = *(const uint4*)(Wt + (size_t)c * 128 + k);
    }
    // stage A tile: 128 rows x 128 cols bf16, 8 iters (zero-pad tail rows)
#pragma unroll
    for (int it = 0; it < 8; ++it) {
        int lin = (it * 256 + tid) * 8;
        int r = lin >> 7;
        int c = lin & 127;
        int row = row0 + r;
        if (row < N) {
            uint4 v = *(const uint4*)(inp + (size_t)row * 128 + c);
            if (BNA) {
                const unsigned short* pv = (const unsigned short*)&v;
                unsigned short o[8];
#pragma unroll
                for (int q = 0; q < 8; ++q)
                    o[q] = f2bf(fmaxf(fmaf(bf2f(pv[q]), u0[c + q], u1[c + q]), 0.f));
                *(uint4*)&As[r][c] = *(const uint4*)o;
            } else {
                *(uint4*)&As[r][c] = v;
            }
        } else {
            uint4 z = {0u, 0u, 0u, 0u};
            *(uint4*)&As[r][c] = z;
        }
    }
    __syncthreads();
    // repurpose u0/u1 as column sum / sumsq accumulators
    if (tid < 128) { u0[tid] = 0.f; u1[tid] = 0.f; }
    __syncthreads();

    const int wave = tid >> 6;
    const int lane = tid & 63;
    const int quad = lane >> 4;
    const int m16  = lane & 15;

    // each wave owns 32 rows: 2 groups of 16. A[m][k] frags -> ds_read_b128
    bf16x8 af[2][4];
#pragma unroll
    for (int g = 0; g < 2; ++g)
#pragma unroll
        for (int kk = 0; kk < 4; ++kk)
            af[g][kk] = *reinterpret_cast<const bf16x8*>(
                &As[wave * 32 + g * 16 + m16][kk * 32 + quad * 8]);

    float* outf = (float*)outv;
    unsigned short* outb = (unsigned short*)outv;

#pragma unroll
    for (int ct = 0; ct < 8; ++ct) {
        f32x4 acc0 = {0.f, 0.f, 0.f, 0.f};
        f32x4 acc1 = {0.f, 0.f, 0.f, 0.f};
#pragma unroll
        for (int kk = 0; kk < 4; ++kk) {
            bf16x8 bf = *reinterpret_cast<const bf16x8*>(&Ws[ct * 16 + m16][kk * 32 + quad * 8]);
            acc0 = __builtin_amdgcn_mfma_f32_16x16x32_bf16(af[0][kk], bf, acc0, 0, 0, 0);
            acc1 = __builtin_amdgcn_mfma_f32_16x16x32_bf16(af[1][kk], bf, acc1, 0, 0, 0);
        }
        int col = ct * 16 + m16;
        float bb = bias[col];
        float s_part = 0.f, q_part = 0.f;
#pragma unroll
        for (int g = 0; g < 2; ++g) {
#pragma unroll
            for (int r = 0; r < 4; ++r) {
                int row = row0 + wave * 32 + g * 16 + quad * 4 + r;  // C/D: row=quad*4+reg
                if (row < N) {
                    float val = (g ? acc1[r] : acc0[r]) + bb;
                    if (OUTBF) outb[(size_t)row * 128 + col] = f2bf(val);
                    else       outf[(size_t)row * 128 + col] = val;
                    s_part += val;
                    q_part += val * val;
                }
            }
        }
        // reduce over the 4 quad-groups that share this column (lanes ^16, ^32)
        s_part += __shfl_xor(s_part, 16); q_part += __shfl_xor(q_part, 16);
        s_part += __shfl_xor(s_part, 32); q_part += __shfl_xor(q_part, 32);
        if (lane < 16) {
            atomicAdd(&u0[col], s_part);
            atomicAdd(&u1[col], q_part);
        }
    }
    __syncthreads();
    if (tid < 128) {
        atomicAdd(&statsOut[tid],       u0[tid]);
        atomicAdd(&statsOut[128 + tid], u1[tid]);
    }
}

// out = gamma * (t - mean) * rsqrt(var + eps) + beta  (final layer, no relu)
__global__ __launch_bounds__(256) void bn_kernel(
    const float* __restrict__ t, const float* __restrict__ sum, const float* __restrict__ sq,
    const float* __restrict__ gamma, const float* __restrict__ beta,
    float* __restrict__ out, int N, int nv4)
{
    __shared__ float sc[128], sh[128];
    int tid = threadIdx.x;
    if (tid < 128) {
        float inv = 1.f / (float)N;
        float m = sum[tid] * inv;
        float v = sq[tid] * inv - m * m;
        v = fmaxf(v, 0.f);
        float rs = rsqrtf(v + 1e-5f);
        float gr = gamma[tid] * rs;
        sc[tid] = gr;
        sh[tid] = beta[tid] - m * gr;
    }
    __syncthreads();
    int g = blockIdx.x * 256 + tid;
    if (g < nv4) {
        int c = (g & 31) * 4;
        float4 v = *(const float4*)(t + (size_t)g * 4);
        float4 o;
        o.x = v.x * sc[c + 0] + sh[c + 0];
        o.y = v.y * sc[c + 1] + sh[c + 1];
        o.z = v.z * sc[c + 2] + sh[c + 2];
        o.w = v.w * sc[c + 3] + sh[c + 3];
        *(float4*)(out + (size_t)g * 4) = o;
    }
}

extern "C" void kernel_launch(void* const* d_in, const int* in_sizes, int n_in,
                              void* d_out, int out_size, void* d_ws, size_t ws_size,
                              hipStream_t stream)
{
    const float* x  = (const float*)d_in[0];
    const int* ei   = (const int*)d_in[1];
    const float* ea = (const float*)d_in[2];
    // d_in[3] = batch (unused)
    const float* W1 = (const float*)d_in[4];
    const float* b1 = (const float*)d_in[5];
    const float* gm = (const float*)d_in[6];
    const float* bm = (const float*)d_in[7];
    const float* W2 = (const float*)d_in[8];
    const float* b2 = (const float*)d_in[9];
    const float* go = (const float*)d_in[10];
    const float* bo = (const float*)d_in[11];
    float* out = (float*)d_out;

    const int N = in_sizes[0] / 128;   // 50000
    const int E = in_sizes[2] / 128;   // 800000

    char* w = (char*)d_ws;
    float* t3   = (float*)w;            w += (size_t)N * 128 * 4;   // gemm2 out (pre-BN2)
    unsigned short* t1 = (unsigned short*)w; w += (size_t)N * 128 * 2;  // agg out, bf16
    unsigned short* t2 = (unsigned short*)w; w += (size_t)N * 128 * 2;  // gemm1 out, bf16
    unsigned short* Wt = (unsigned short*)w; w += (size_t)6 * 16384 * 2; // W bf16 [c][k]
    float* stats = (float*)w;           w += 1536 * 4;              // 6 x (sum[128], sq[128])
    int* i64flag = (int*)w;             w += 16;
    int* counts  = (int*)w;             w += (size_t)N * 4;
    int* offs    = (int*)w;             w += (size_t)(N + 16) * 4;  // N+1 entries
    int* cursor  = (int*)w;             w += (size_t)N * 4;
    int* bsum    = (int*)w;             w += 256 * 4;
    int2* el     = (int2*)w;            w += (size_t)E * 8;         // CSR: (src, edge)

    const int nv4 = N * 32;
    const int gElem = (nv4 + 255) / 256;
    const int gGemm = (N + 127) / 128;
    const int gEdge = (E + 255) / 256;
    const int nb    = (N + 255) / 256;
    const int gAgg  = (N + 7) / 8;
    const int gSetup = 12288 / 256 > nb ? 12288 / 256 : nb;

    // ---- CSR build + W pre-convert (both layer-invariant) ----
    setup_kernel<<<gSetup, 256, 0, stream>>>(ei, i64flag, counts, stats, W1, W2, Wt, N);
    hist_kernel<<<gEdge, 256, 0, stream>>>(ei, i64flag, counts, E);
    scan1_kernel<<<nb, 256, 0, stream>>>(counts, offs, bsum, N);
    scan23_kernel<<<nb, 256, 0, stream>>>(offs, bsum, cursor, N, E, nb);
    scatter_kernel<<<gEdge, 256, 0, stream>>>(ei, i64flag, cursor, el, E);

    for (int i = 0; i < 3; ++i) {
        float* sMlp = stats + (size_t)i * 512;        // gemm1 output stats
        float* sOut = stats + (size_t)i * 512 + 256;  // gemm2 output stats

        if (i == 0) {
            agg_kernel<false><<<gAgg, 512, 0, stream>>>(
                x, ea, el, offs, nullptr, nullptr, nullptr, t1, N);
        } else {
            float* sPrev = stats + (size_t)(i - 1) * 512 + 256;
            agg_kernel<true><<<gAgg, 512, 0, stream>>>(
                t3, ea, el, offs, sPrev, go + (i - 1) * 128, bo + (i - 1) * 128, t1, N);
        }
        // gemm1: t1 (bf16) -> t2 (bf16), stats of t2 -> sMlp
        gemm_kernel<false, true><<<gGemm, 256, 0, stream>>>(
            t1, Wt + (size_t)i * 16384, b1 + i * 128,
            nullptr, nullptr, nullptr, t2, sMlp, N);
        // gemm2: BN1+relu applied to t2 -> t3 (f32), stats of t3 -> sOut
        gemm_kernel<true, false><<<gGemm, 256, 0, stream>>>(
            t2, Wt + (size_t)(i + 3) * 16384, b2 + i * 128,
            sMlp, gm + i * 128, bm + i * 128, t3, sOut, N);
    }
    // final outer BN (no relu) -> out
    bn_kernel<<<gElem, 256, 0, stream>>>(t3, stats + 2 * 512 + 256, stats + 2 * 512 + 384,
                                         go + 256, bo + 256, out, N, nv4);
}

// Round 11
// 1005.405 us; speedup vs baseline: 1.2842x; 1.0600x over previous
//
#include <hip/hip_runtime.h>

#define DEV __device__ __forceinline__

typedef __bf16 bf16x8 __attribute__((ext_vector_type(8)));
typedef float f32x4 __attribute__((ext_vector_type(4)));
typedef unsigned short u16x4 __attribute__((ext_vector_type(4)));

DEV unsigned short f2bf(float f) {
    unsigned u = __builtin_bit_cast(unsigned, f);
    u += 0x7fffu + ((u >> 16) & 1u);   // round-to-nearest-even
    return (unsigned short)(u >> 16);
}

DEV float bf2f(unsigned short h) {
    unsigned u = (unsigned)h << 16;
    return __builtin_bit_cast(float, u);
}

// zero counts[N] + stats[1536]; pre-convert W1,W2 (6 mats) to bf16 [c][k];
// convert x -> xb bf16; block 0 detects int64-vs-int32 edge_index layout.
__global__ __launch_bounds__(256) void setup_kernel(
    const int* __restrict__ ei, int* __restrict__ flag,
    int* __restrict__ counts, float* __restrict__ stats,
    const float* __restrict__ W1, const float* __restrict__ W2,
    unsigned short* __restrict__ Wt,
    const float* __restrict__ x, unsigned short* __restrict__ xb, int N)
{
    int g = blockIdx.x * 256 + threadIdx.x;
    if (g < N) counts[g] = 0;
    if (g < 1536) stats[g] = 0.f;
    if (g < 12288) {                       // 6 mats x 16 k-groups x 128 cols
        int mat = g >> 11;
        int r = g & 2047;
        int c = r & 127;
        int kg = (r >> 7) * 8;
        const float* Wsrc = (mat < 3) ? (W1 + (size_t)mat * 16384)
                                      : (W2 + (size_t)(mat - 3) * 16384);
        unsigned short o[8];
#pragma unroll
        for (int q = 0; q < 8; ++q)
            o[q] = f2bf(Wsrc[(size_t)(kg + q) * 128 + c]);
        *(uint4*)(Wt + ((size_t)mat * 128 + c) * 128 + kg) = *(const uint4*)o;
    }
    // x -> xb bf16 (8 elems/thread); N*16 threads cover N*128
    if (g < N * 16) {
        size_t base = (size_t)g * 8;
        float4 a = *(const float4*)(x + base);
        float4 b = *(const float4*)(x + base + 4);
        unsigned short o[8];
        o[0] = f2bf(a.x); o[1] = f2bf(a.y); o[2] = f2bf(a.z); o[3] = f2bf(a.w);
        o[4] = f2bf(b.x); o[5] = f2bf(b.y); o[6] = f2bf(b.z); o[7] = f2bf(b.w);
        *(uint4*)(xb + base) = *(const uint4*)o;
    }
    if (blockIdx.x == 0 && threadIdx.x < 64) {
        int t = threadIdx.x;
        int v = (t < 32) ? ei[2 * t + 1] : 0;
        unsigned long long b = __ballot(v == 0);
        if (t == 0) *flag = (b == ~0ull) ? 1 : 0;
    }
}

__global__ __launch_bounds__(256) void hist_kernel(
    const int* __restrict__ ei, const int* __restrict__ i64flag,
    int* __restrict__ counts, int E)
{
    int e = blockIdx.x * 256 + threadIdx.x;
    if (e >= E) return;
    int d = (*i64flag) ? ei[2 * (size_t)E + 2 * (size_t)e] : ei[(size_t)E + e];
    atomicAdd(&counts[d], 1);
}

// block-level inclusive scan; writes per-element exclusive offsets + block totals
__global__ __launch_bounds__(256) void scan1_kernel(
    const int* __restrict__ counts, int* __restrict__ offs,
    int* __restrict__ bsum, int N)
{
    __shared__ int s[256];
    int tid = threadIdx.x;
    int i = blockIdx.x * 256 + tid;
    int c = (i < N) ? counts[i] : 0;
    s[tid] = c;
    __syncthreads();
#pragma unroll
    for (int off = 1; off < 256; off <<= 1) {
        int add = (tid >= off) ? s[tid - off] : 0;
        __syncthreads();
        s[tid] += add;
        __syncthreads();
    }
    int incl = s[tid];
    if (i < N) offs[i] = incl - c;            // exclusive within block
    if (tid == 255) bsum[blockIdx.x] = incl;  // block total
}

// merged scan2+scan3: every block re-scans the (<=256) block sums in LDS,
// adds its prefix to offs, fills cursor, and block 0 writes offs[N] = E.
__global__ __launch_bounds__(256) void scan23_kernel(
    int* __restrict__ offs, const int* __restrict__ bsum,
    int* __restrict__ cursor, int N, int E, int nb)
{
    __shared__ int s[256];
    int tid = threadIdx.x;
    int v = (tid < nb) ? bsum[tid] : 0;
    s[tid] = v;
    __syncthreads();
#pragma unroll
    for (int off = 1; off < 256; off <<= 1) {
        int add = (tid >= off) ? s[tid - off] : 0;
        __syncthreads();
        s[tid] += add;
        __syncthreads();
    }
    int pre = (blockIdx.x == 0) ? 0 : s[blockIdx.x - 1];
    int i = blockIdx.x * 256 + tid;
    if (i < N) {
        int o = offs[i] + pre;
        offs[i] = o;
        cursor[i] = o;
    }
    if (blockIdx.x == 0 && tid == 0) offs[N] = E;
}

// CSR scatter: el[slot] = (src, edge_id)
__global__ __launch_bounds__(256) void scatter_kernel(
    const int* __restrict__ ei, const int* __restrict__ i64flag,
    int* __restrict__ cursor, int2* __restrict__ el, int E)
{
    int e = blockIdx.x * 256 + threadIdx.x;
    if (e >= E) return;
    int s, d;
    if (*i64flag) {
        s = ei[2 * (size_t)e];
        d = ei[2 * (size_t)E + 2 * (size_t)e];
    } else {
        s = ei[e];
        d = ei[(size_t)E + e];
    }
    int pos = atomicAdd(&cursor[d], 1);
    el[pos] = make_int2(s, e);
}

// ---------------- aggregation ----------------
// t1[n] (bf16) = xbn[n] + sum_{slot in CSR[n]} relu(xbn[el[slot].x] + ea[el[slot].y])
// x input is bf16 (halved gather bytes); ea stays f32. xbn = AFFINE ?
// relu(x*sc+sh) : x. One wave per node; half-wave 0 takes the first
// ceil(deg/2) CSR slots, half 1 the rest. 4-edge unroll for MLP.
template<bool AFFINE>
__global__ __launch_bounds__(512) void agg_kernel(
    const unsigned short* __restrict__ xb, const float* __restrict__ ea,
    const int2* __restrict__ el, const int* __restrict__ offs,
    const float* __restrict__ statsIn, const float* __restrict__ gamma,
    const float* __restrict__ beta,
    unsigned short* __restrict__ t1, int N)
{
    __shared__ float sc[128], sh[128];
    int tid = threadIdx.x;
    if (AFFINE) {
        if (tid < 128) {
            float inv = 1.f / (float)N;
            float m = statsIn[tid] * inv;
            float v = statsIn[128 + tid] * inv - m * m;
            v = fmaxf(v, 0.f);
            float rs = rsqrtf(v + 1e-5f);
            float gr = gamma[tid] * rs;
            sc[tid] = gr;
            sh[tid] = beta[tid] - m * gr;
        }
        __syncthreads();
    }

    const int lane = tid & 63;
    const int half = lane >> 5;
    const int l32  = lane & 31;
    const int d0   = l32 * 4;

    f32x4 scv = {1.f, 1.f, 1.f, 1.f}, shv = {0.f, 0.f, 0.f, 0.f};
    if (AFFINE) {
        scv = *(const f32x4*)(sc + d0);
        shv = *(const f32x4*)(sh + d0);
    }

    const int n = blockIdx.x * 8 + (tid >> 6);
    if (n >= N) return;

    const int start = offs[n];
    const int deg   = offs[n + 1] - start;
    const int mid = (deg + 1) >> 1;
    int j        = half ? mid : 0;
    const int hi = half ? deg : mid;

    f32x4 acc = {0.f, 0.f, 0.f, 0.f};
    if (half == 0) {
        u16x4 cv = *(const u16x4*)(xb + (size_t)n * 128 + d0);
#pragma unroll
        for (int q = 0; q < 4; ++q) {
            float f = bf2f(cv[q]);
            if (AFFINE) f = fmaxf(fmaf(f, scv[q], shv[q]), 0.f);
            acc[q] = f;
        }
    }

#define APPLY(GXV, AV) { \
    _Pragma("unroll") \
    for (int q = 0; q < 4; ++q) { \
        float gx = bf2f((GXV)[q]); \
        if (AFFINE) gx = fmaxf(fmaf(gx, scv[q], shv[q]), 0.f); \
        acc[q] += fmaxf(gx + (AV)[q], 0.f); \
    } }

    for (; j + 3 < hi; j += 4) {
        int2 e0 = el[start + j + 0];
        int2 e1 = el[start + j + 1];
        int2 e2 = el[start + j + 2];
        int2 e3 = el[start + j + 3];
        u16x4 x0 = *(const u16x4*)(xb + (size_t)e0.x * 128 + d0);
        u16x4 x1 = *(const u16x4*)(xb + (size_t)e1.x * 128 + d0);
        u16x4 x2 = *(const u16x4*)(xb + (size_t)e2.x * 128 + d0);
        u16x4 x3 = *(const u16x4*)(xb + (size_t)e3.x * 128 + d0);
        f32x4 a0 = __builtin_nontemporal_load((const f32x4*)(ea + (size_t)e0.y * 128 + d0));
        f32x4 a1 = __builtin_nontemporal_load((const f32x4*)(ea + (size_t)e1.y * 128 + d0));
        f32x4 a2 = __builtin_nontemporal_load((const f32x4*)(ea + (size_t)e2.y * 128 + d0));
        f32x4 a3 = __builtin_nontemporal_load((const f32x4*)(ea + (size_t)e3.y * 128 + d0));
        APPLY(x0, a0); APPLY(x1, a1); APPLY(x2, a2); APPLY(x3, a3);
    }
    for (; j < hi; ++j) {
        int2 e0 = el[start + j];
        u16x4 x0 = *(const u16x4*)(xb + (size_t)e0.x * 128 + d0);
        f32x4 a0 = __builtin_nontemporal_load((const f32x4*)(ea + (size_t)e0.y * 128 + d0));
        APPLY(x0, a0);
    }
#undef APPLY

    // combine the two half-wave partial sums
#pragma unroll
    for (int q = 0; q < 4; ++q) acc[q] += __shfl_xor(acc[q], 32);

    if (half == 0) {
        u16x4 o;
        o[0] = f2bf(acc[0]); o[1] = f2bf(acc[1]);
        o[2] = f2bf(acc[2]); o[3] = f2bf(acc[3]);
        *(u16x4*)(t1 + (size_t)n * 128 + d0) = o;
    }
}

// ---------------- GEMM 128x128 tile, 8 waves, fused BN-affine + col stats
// out[n][c] = sum_k a[n][k]*Wt[c][k] + bias[c].  Wt bf16 [c][k]; inp bf16.
// BNA: a = bf16(relu(inp*sc+sh)); else a = inp.
// OUTBF: out stored bf16, else f32. Stats accumulate on pre-round f32 values.
template<bool BNA, bool OUTBF>
__global__ __launch_bounds__(512) void gemm_kernel(
    const unsigned short* __restrict__ inp,   // [N][128] bf16
    const unsigned short* __restrict__ Wt,    // [128][128] bf16, [c][k]
    const float* __restrict__ bias,           // [128] f32
    const float* __restrict__ statsIn,
    const float* __restrict__ gA, const float* __restrict__ bA,
    void* __restrict__ outv, float* __restrict__ statsOut, int N)
{
    __shared__ __attribute__((aligned(16))) unsigned short As[128][136];  // [r][k]
    __shared__ __attribute__((aligned(16))) unsigned short Ws[128][136];  // [c][k]
    __shared__ float u0[128], u1[128];  // BNA: sc/sh during staging; then stats
    const int tid = threadIdx.x;
    const int row0 = blockIdx.x * 128;

    if (BNA) {
        if (tid < 128) {
            float inv = 1.f / (float)N;
            float m = statsIn[tid] * inv;
            float v = statsIn[128 + tid] * inv - m * m;
            v = fmaxf(v, 0.f);
            float rs = rsqrtf(v + 1e-5f);
            float gr = gA[tid] * rs;
            u0[tid] = gr;
            u1[tid] = bA[tid] - m * gr;
        }
        __syncthreads();
    }

    // stage Wt -> Ws: 16384 elems, 512 thr x 8 elems x 4 iters
#pragma unroll
    for (int it = 0; it < 4; ++it) {
        int lin = (it * 512 + tid) * 8;
        int c = lin >> 7;
        int k = lin & 127;
        *(uint4*)&Ws[c][k] = *(const uint4*)(Wt + (size_t)c * 128 + k);
    }
    // stage A tile: 128x128 bf16, 4 iters (zero-pad tail rows)
#pragma unroll
    for (int it = 0; it < 4; ++it) {
        int lin = (it * 512 + tid) * 8;
        int r = lin >> 7;
        int c = lin & 127;
        int row = row0 + r;
        if (row < N) {
            uint4 v = *(const uint4*)(inp + (size_t)row * 128 + c);
            if (BNA) {
                const unsigned short* pv = (const unsigned short*)&v;
                unsigned short o[8];
#pragma unroll
                for (int q = 0; q < 8; ++q)
                    o[q] = f2bf(fmaxf(fmaf(bf2f(pv[q]), u0[c + q], u1[c + q]), 0.f));
                *(uint4*)&As[r][c] = *(const uint4*)o;
            } else {
                *(uint4*)&As[r][c] = v;
            }
        } else {
            uint4 z = {0u, 0u, 0u, 0u};
            *(uint4*)&As[r][c] = z;
        }
    }
    __syncthreads();
    // repurpose u0/u1 as column sum / sumsq accumulators
    if (tid < 128) { u0[tid] = 0.f; u1[tid] = 0.f; }
    __syncthreads();

    const int wave = tid >> 6;          // 0..7, owns rows wave*16..+15
    const int lane = tid & 63;
    const int quad = lane >> 4;
    const int m16  = lane & 15;

    bf16x8 af[4];
#pragma unroll
    for (int kk = 0; kk < 4; ++kk)
        af[kk] = *reinterpret_cast<const bf16x8*>(
            &As[wave * 16 + m16][kk * 32 + quad * 8]);

    float* outf = (float*)outv;
    unsigned short* outb = (unsigned short*)outv;

#pragma unroll
    for (int ct = 0; ct < 8; ++ct) {
        f32x4 acc = {0.f, 0.f, 0.f, 0.f};
#pragma unroll
        for (int kk = 0; kk < 4; ++kk) {
            bf16x8 bf = *reinterpret_cast<const bf16x8*>(&Ws[ct * 16 + m16][kk * 32 + quad * 8]);
            acc = __builtin_amdgcn_mfma_f32_16x16x32_bf16(af[kk], bf, acc, 0, 0, 0);
        }
        int col = ct * 16 + m16;
        float bb = bias[col];
        float s_part = 0.f, q_part = 0.f;
#pragma unroll
        for (int r = 0; r < 4; ++r) {
            int row = row0 + wave * 16 + quad * 4 + r;  // C/D: row = quad*4+reg
            if (row < N) {
                float val = acc[r] + bb;
                if (OUTBF) outb[(size_t)row * 128 + col] = f2bf(val);
                else       outf[(size_t)row * 128 + col] = val;
                s_part += val;
                q_part += val * val;
            }
        }
        // reduce over the 4 quad-groups that share this column (lanes ^16, ^32)
        s_part += __shfl_xor(s_part, 16); q_part += __shfl_xor(q_part, 16);
        s_part += __shfl_xor(s_part, 32); q_part += __shfl_xor(q_part, 32);
        if (lane < 16) {
            atomicAdd(&u0[col], s_part);
            atomicAdd(&u1[col], q_part);
        }
    }
    __syncthreads();
    if (tid < 128) {
        atomicAdd(&statsOut[tid],       u0[tid]);
        atomicAdd(&statsOut[128 + tid], u1[tid]);
    }
}

// out = gamma * (t - mean) * rsqrt(var + eps) + beta  (final layer, no relu)
__global__ __launch_bounds__(256) void bn_kernel(
    const float* __restrict__ t, const float* __restrict__ sum, const float* __restrict__ sq,
    const float* __restrict__ gamma, const float* __restrict__ beta,
    float* __restrict__ out, int N, int nv4)
{
    __shared__ float sc[128], sh[128];
    int tid = threadIdx.x;
    if (tid < 128) {
        float inv = 1.f / (float)N;
        float m = sum[tid] * inv;
        float v = sq[tid] * inv - m * m;
        v = fmaxf(v, 0.f);
        float rs = rsqrtf(v + 1e-5f);
        float gr = gamma[tid] * rs;
        sc[tid] = gr;
        sh[tid] = beta[tid] - m * gr;
    }
    __syncthreads();
    int g = blockIdx.x * 256 + tid;
    if (g < nv4) {
        int c = (g & 31) * 4;
        float4 v = *(const float4*)(t + (size_t)g * 4);
        float4 o;
        o.x = v.x * sc[c + 0] + sh[c + 0];
        o.y = v.y * sc[c + 1] + sh[c + 1];
        o.z = v.z * sc[c + 2] + sh[c + 2];
        o.w = v.w * sc[c + 3] + sh[c + 3];
        *(float4*)(out + (size_t)g * 4) = o;
    }
}

extern "C" void kernel_launch(void* const* d_in, const int* in_sizes, int n_in,
                              void* d_out, int out_size, void* d_ws, size_t ws_size,
                              hipStream_t stream)
{
    const float* x  = (const float*)d_in[0];
    const int* ei   = (const int*)d_in[1];
    const float* ea = (const float*)d_in[2];
    // d_in[3] = batch (unused)
    const float* W1 = (const float*)d_in[4];
    const float* b1 = (const float*)d_in[5];
    const float* gm = (const float*)d_in[6];
    const float* bm = (const float*)d_in[7];
    const float* W2 = (const float*)d_in[8];
    const float* b2 = (const float*)d_in[9];
    const float* go = (const float*)d_in[10];
    const float* bo = (const float*)d_in[11];
    float* out = (float*)d_out;

    const int N = in_sizes[0] / 128;   // 50000
    const int E = in_sizes[2] / 128;   // 800000

    char* w = (char*)d_ws;
    float* t3f  = (float*)w;            w += (size_t)N * 128 * 4;   // layer-2 gemm2 out, f32
    unsigned short* t3b = (unsigned short*)w; w += (size_t)N * 128 * 2;  // layers 0/1 gemm2 out
    unsigned short* t1 = (unsigned short*)w; w += (size_t)N * 128 * 2;  // agg out, bf16
    unsigned short* t2 = (unsigned short*)w; w += (size_t)N * 128 * 2;  // gemm1 out, bf16
    unsigned short* xb = (unsigned short*)w; w += (size_t)N * 128 * 2;  // x bf16 (layer 0)
    unsigned short* Wt = (unsigned short*)w; w += (size_t)6 * 16384 * 2; // W bf16 [c][k]
    float* stats = (float*)w;           w += 1536 * 4;              // 6 x (sum[128], sq[128])
    int* i64flag = (int*)w;             w += 16;
    int* counts  = (int*)w;             w += (size_t)N * 4;
    int* offs    = (int*)w;             w += (size_t)(N + 16) * 4;  // N+1 entries
    int* cursor  = (int*)w;             w += (size_t)N * 4;
    int* bsum    = (int*)w;             w += 256 * 4;
    int2* el     = (int2*)w;            w += (size_t)E * 8;         // CSR: (src, edge)

    const int nv4 = N * 32;
    const int gElem = (nv4 + 255) / 256;
    const int gGemm = (N + 127) / 128;
    const int gEdge = (E + 255) / 256;
    const int nb    = (N + 255) / 256;
    const int gAgg  = (N + 7) / 8;
    const int gConv = (N * 16 + 255) / 256;
    const int gSetup = gConv > nb ? gConv : nb;

    // ---- CSR build + W/x pre-convert (all layer-invariant) ----
    setup_kernel<<<gSetup, 256, 0, stream>>>(ei, i64flag, counts, stats, W1, W2, Wt, x, xb, N);
    hist_kernel<<<gEdge, 256, 0, stream>>>(ei, i64flag, counts, E);
    scan1_kernel<<<nb, 256, 0, stream>>>(counts, offs, bsum, N);
    scan23_kernel<<<nb, 256, 0, stream>>>(offs, bsum, cursor, N, E, nb);
    scatter_kernel<<<gEdge, 256, 0, stream>>>(ei, i64flag, cursor, el, E);

    for (int i = 0; i < 3; ++i) {
        float* sMlp = stats + (size_t)i * 512;        // gemm1 output stats
        float* sOut = stats + (size_t)i * 512 + 256;  // gemm2 output stats

        if (i == 0) {
            agg_kernel<false><<<gAgg, 512, 0, stream>>>(
                xb, ea, el, offs, nullptr, nullptr, nullptr, t1, N);
        } else {
            float* sPrev = stats + (size_t)(i - 1) * 512 + 256;
            agg_kernel<true><<<gAgg, 512, 0, stream>>>(
                t3b, ea, el, offs, sPrev, go + (i - 1) * 128, bo + (i - 1) * 128, t1, N);
        }
        // gemm1: t1 (bf16) -> t2 (bf16), stats of t2 -> sMlp
        gemm_kernel<false, true><<<gGemm, 512, 0, stream>>>(
            t1, Wt + (size_t)i * 16384, b1 + i * 128,
            nullptr, nullptr, nullptr, t2, sMlp, N);
        // gemm2: BN1+relu applied to t2; layers 0/1 -> t3b (bf16), layer 2 -> t3f (f32)
        if (i < 2) {
            gemm_kernel<true, true><<<gGemm, 512, 0, stream>>>(
                t2, Wt + (size_t)(i + 3) * 16384, b2 + i * 128,
                sMlp, gm + i * 128, bm + i * 128, t3b, sOut, N);
        } else {
            gemm_kernel<true, false><<<gGemm, 512, 0, stream>>>(
                t2, Wt + (size_t)(i + 3) * 16384, b2 + i * 128,
                sMlp, gm + i * 128, bm + i * 128, t3f, sOut, N);
        }
    }
    // final outer BN (no relu) -> out
    bn_kernel<<<gElem, 256, 0, stream>>>(t3f, stats + 2 * 512 + 256, stats + 2 * 512 + 384,
                                         go + 256, bo + 256, out, N, nv4);
}

// Round 12
// 985.883 us; speedup vs baseline: 1.3097x; 1.0198x over previous
//
#include <hip/hip_runtime.h>

#define DEV __device__ __forceinline__

typedef __bf16 bf16x8 __attribute__((ext_vector_type(8)));
typedef float f32x4 __attribute__((ext_vector_type(4)));
typedef unsigned short u16x4 __attribute__((ext_vector_type(4)));

DEV unsigned short f2bf(float f) {
    unsigned u = __builtin_bit_cast(unsigned, f);
    u += 0x7fffu + ((u >> 16) & 1u);   // round-to-nearest-even
    return (unsigned short)(u >> 16);
}

DEV float bf2f(unsigned short h) {
    unsigned u = (unsigned)h << 16;
    return __builtin_bit_cast(float, u);
}

// zero counts[N] + stats[1536]; pre-convert W1,W2 (6 mats) to bf16 [c][k];
// convert x -> xb bf16; block 0 detects int64-vs-int32 edge_index layout.
__global__ __launch_bounds__(256) void setup_kernel(
    const int* __restrict__ ei, int* __restrict__ flag,
    int* __restrict__ counts, float* __restrict__ stats,
    const float* __restrict__ W1, const float* __restrict__ W2,
    unsigned short* __restrict__ Wt,
    const float* __restrict__ x, unsigned short* __restrict__ xb, int N)
{
    int g = blockIdx.x * 256 + threadIdx.x;
    if (g < N) counts[g] = 0;
    if (g < 1536) stats[g] = 0.f;
    if (g < 12288) {                       // 6 mats x 16 k-groups x 128 cols
        int mat = g >> 11;
        int r = g & 2047;
        int c = r & 127;
        int kg = (r >> 7) * 8;
        const float* Wsrc = (mat < 3) ? (W1 + (size_t)mat * 16384)
                                      : (W2 + (size_t)(mat - 3) * 16384);
        unsigned short o[8];
#pragma unroll
        for (int q = 0; q < 8; ++q)
            o[q] = f2bf(Wsrc[(size_t)(kg + q) * 128 + c]);
        *(uint4*)(Wt + ((size_t)mat * 128 + c) * 128 + kg) = *(const uint4*)o;
    }
    // x -> xb bf16 (8 elems/thread); N*16 threads cover N*128
    if (g < N * 16) {
        size_t base = (size_t)g * 8;
        float4 a = *(const float4*)(x + base);
        float4 b = *(const float4*)(x + base + 4);
        unsigned short o[8];
        o[0] = f2bf(a.x); o[1] = f2bf(a.y); o[2] = f2bf(a.z); o[3] = f2bf(a.w);
        o[4] = f2bf(b.x); o[5] = f2bf(b.y); o[6] = f2bf(b.z); o[7] = f2bf(b.w);
        *(uint4*)(xb + base) = *(const uint4*)o;
    }
    if (blockIdx.x == 0 && threadIdx.x < 64) {
        int t = threadIdx.x;
        int v = (t < 32) ? ei[2 * t + 1] : 0;
        unsigned long long b = __ballot(v == 0);
        if (t == 0) *flag = (b == ~0ull) ? 1 : 0;
    }
}

__global__ __launch_bounds__(256) void hist_kernel(
    const int* __restrict__ ei, const int* __restrict__ i64flag,
    int* __restrict__ counts, int E)
{
    int e = blockIdx.x * 256 + threadIdx.x;
    if (e >= E) return;
    int d = (*i64flag) ? ei[2 * (size_t)E + 2 * (size_t)e] : ei[(size_t)E + e];
    atomicAdd(&counts[d], 1);
}

// block-level inclusive scan; writes per-element exclusive offsets + block totals
__global__ __launch_bounds__(256) void scan1_kernel(
    const int* __restrict__ counts, int* __restrict__ offs,
    int* __restrict__ bsum, int N)
{
    __shared__ int s[256];
    int tid = threadIdx.x;
    int i = blockIdx.x * 256 + tid;
    int c = (i < N) ? counts[i] : 0;
    s[tid] = c;
    __syncthreads();
#pragma unroll
    for (int off = 1; off < 256; off <<= 1) {
        int add = (tid >= off) ? s[tid - off] : 0;
        __syncthreads();
        s[tid] += add;
        __syncthreads();
    }
    int incl = s[tid];
    if (i < N) offs[i] = incl - c;            // exclusive within block
    if (tid == 255) bsum[blockIdx.x] = incl;  // block total
}

// merged scan2+scan3: every block re-scans the (<=256) block sums in LDS,
// adds its prefix to offs, fills cursor, and block 0 writes offs[N] = E.
__global__ __launch_bounds__(256) void scan23_kernel(
    int* __restrict__ offs, const int* __restrict__ bsum,
    int* __restrict__ cursor, int N, int E, int nb)
{
    __shared__ int s[256];
    int tid = threadIdx.x;
    int v = (tid < nb) ? bsum[tid] : 0;
    s[tid] = v;
    __syncthreads();
#pragma unroll
    for (int off = 1; off < 256; off <<= 1) {
        int add = (tid >= off) ? s[tid - off] : 0;
        __syncthreads();
        s[tid] += add;
        __syncthreads();
    }
    int pre = (blockIdx.x == 0) ? 0 : s[blockIdx.x - 1];
    int i = blockIdx.x * 256 + tid;
    if (i < N) {
        int o = offs[i] + pre;
        offs[i] = o;
        cursor[i] = o;
    }
    if (blockIdx.x == 0 && tid == 0) offs[N] = E;
}

// CSR scatter: el[slot] = (src, edge_id)
__global__ __launch_bounds__(256) void scatter_kernel(
    const int* __restrict__ ei, const int* __restrict__ i64flag,
    int* __restrict__ cursor, int2* __restrict__ el, int E)
{
    int e = blockIdx.x * 256 + threadIdx.x;
    if (e >= E) return;
    int s, d;
    if (*i64flag) {
        s = ei[2 * (size_t)e];
        d = ei[2 * (size_t)E + 2 * (size_t)e];
    } else {
        s = ei[e];
        d = ei[(size_t)E + e];
    }
    int pos = atomicAdd(&cursor[d], 1);
    el[pos] = make_int2(s, e);
}

// ---------------- aggregation ----------------
// t1[n] (bf16) = xbn[n] + sum_{slot in CSR[n]} relu(xbn[src] + ea_slot)
// MODE 0 (layer 0): no affine; ea_slot read f32 via el[slot].y (random row);
//   ALSO writes eab[slot] = bf16(ea_slot) -- sequential per node -- so later
//   layers stream it.
// MODE 1 (layers 1,2): affine (prev outer BN+ReLU folded); ea_slot read from
//   eab (bf16, sequential by slot -- half bytes, streaming).
// One wave per node; half-wave 0 takes the first ceil(deg/2) CSR slots,
// half 1 the rest. 4-edge unroll keeps 8 gathers in flight per half-wave.
template<int MODE>
__global__ __launch_bounds__(512) void agg_kernel(
    const unsigned short* __restrict__ xb, const float* __restrict__ ea,
    unsigned short* __restrict__ eab,
    const int2* __restrict__ el, const int* __restrict__ offs,
    const float* __restrict__ statsIn, const float* __restrict__ gamma,
    const float* __restrict__ beta,
    unsigned short* __restrict__ t1, int N)
{
    constexpr bool AFFINE = (MODE == 1);
    __shared__ float sc[128], sh[128];
    int tid = threadIdx.x;
    if (AFFINE) {
        if (tid < 128) {
            float inv = 1.f / (float)N;
            float m = statsIn[tid] * inv;
            float v = statsIn[128 + tid] * inv - m * m;
            v = fmaxf(v, 0.f);
            float rs = rsqrtf(v + 1e-5f);
            float gr = gamma[tid] * rs;
            sc[tid] = gr;
            sh[tid] = beta[tid] - m * gr;
        }
        __syncthreads();
    }

    const int lane = tid & 63;
    const int half = lane >> 5;
    const int l32  = lane & 31;
    const int d0   = l32 * 4;

    f32x4 scv = {1.f, 1.f, 1.f, 1.f}, shv = {0.f, 0.f, 0.f, 0.f};
    if (AFFINE) {
        scv = *(const f32x4*)(sc + d0);
        shv = *(const f32x4*)(sh + d0);
    }

    const int n = blockIdx.x * 8 + (tid >> 6);
    if (n >= N) return;

    const int start = offs[n];
    const int deg   = offs[n + 1] - start;
    const int mid = (deg + 1) >> 1;
    int j        = half ? mid : 0;
    const int hi = half ? deg : mid;

    f32x4 acc = {0.f, 0.f, 0.f, 0.f};
    if (half == 0) {
        u16x4 cv = *(const u16x4*)(xb + (size_t)n * 128 + d0);
#pragma unroll
        for (int q = 0; q < 4; ++q) {
            float f = bf2f(cv[q]);
            if (AFFINE) f = fmaxf(fmaf(f, scv[q], shv[q]), 0.f);
            acc[q] = f;
        }
    }

    // one edge at CSR slot S with x-row fragment GXV and ea f32x4 AV
#define APPLY(GXV, AV) { \
    _Pragma("unroll") \
    for (int q = 0; q < 4; ++q) { \
        float gx = bf2f((GXV)[q]); \
        if (AFFINE) gx = fmaxf(fmaf(gx, scv[q], shv[q]), 0.f); \
        acc[q] += fmaxf(gx + (AV)[q], 0.f); \
    } }

    if (MODE == 0) {
        for (; j + 3 < hi; j += 4) {
            int2 e0 = el[start + j + 0];
            int2 e1 = el[start + j + 1];
            int2 e2 = el[start + j + 2];
            int2 e3 = el[start + j + 3];
            u16x4 x0 = *(const u16x4*)(xb + (size_t)e0.x * 128 + d0);
            u16x4 x1 = *(const u16x4*)(xb + (size_t)e1.x * 128 + d0);
            u16x4 x2 = *(const u16x4*)(xb + (size_t)e2.x * 128 + d0);
            u16x4 x3 = *(const u16x4*)(xb + (size_t)e3.x * 128 + d0);
            f32x4 a0 = __builtin_nontemporal_load((const f32x4*)(ea + (size_t)e0.y * 128 + d0));
            f32x4 a1 = __builtin_nontemporal_load((const f32x4*)(ea + (size_t)e1.y * 128 + d0));
            f32x4 a2 = __builtin_nontemporal_load((const f32x4*)(ea + (size_t)e2.y * 128 + d0));
            f32x4 a3 = __builtin_nontemporal_load((const f32x4*)(ea + (size_t)e3.y * 128 + d0));
            u16x4 b0, b1, b2, b3;
#pragma unroll
            for (int q = 0; q < 4; ++q) {
                b0[q] = f2bf(a0[q]); b1[q] = f2bf(a1[q]);
                b2[q] = f2bf(a2[q]); b3[q] = f2bf(a3[q]);
            }
            __builtin_nontemporal_store(b0, (u16x4*)(eab + (size_t)(start + j + 0) * 128 + d0));
            __builtin_nontemporal_store(b1, (u16x4*)(eab + (size_t)(start + j + 1) * 128 + d0));
            __builtin_nontemporal_store(b2, (u16x4*)(eab + (size_t)(start + j + 2) * 128 + d0));
            __builtin_nontemporal_store(b3, (u16x4*)(eab + (size_t)(start + j + 3) * 128 + d0));
            APPLY(x0, a0); APPLY(x1, a1); APPLY(x2, a2); APPLY(x3, a3);
        }
        for (; j < hi; ++j) {
            int2 e0 = el[start + j];
            u16x4 x0 = *(const u16x4*)(xb + (size_t)e0.x * 128 + d0);
            f32x4 a0 = __builtin_nontemporal_load((const f32x4*)(ea + (size_t)e0.y * 128 + d0));
            u16x4 b0;
#pragma unroll
            for (int q = 0; q < 4; ++q) b0[q] = f2bf(a0[q]);
            __builtin_nontemporal_store(b0, (u16x4*)(eab + (size_t)(start + j) * 128 + d0));
            APPLY(x0, a0);
        }
    } else {
        for (; j + 3 < hi; j += 4) {
            int2 e0 = el[start + j + 0];
            int2 e1 = el[start + j + 1];
            int2 e2 = el[start + j + 2];
            int2 e3 = el[start + j + 3];
            u16x4 x0 = *(const u16x4*)(xb + (size_t)e0.x * 128 + d0);
            u16x4 x1 = *(const u16x4*)(xb + (size_t)e1.x * 128 + d0);
            u16x4 x2 = *(const u16x4*)(xb + (size_t)e2.x * 128 + d0);
            u16x4 x3 = *(const u16x4*)(xb + (size_t)e3.x * 128 + d0);
            u16x4 g0 = __builtin_nontemporal_load((const u16x4*)(eab + (size_t)(start + j + 0) * 128 + d0));
            u16x4 g1 = __builtin_nontemporal_load((const u16x4*)(eab + (size_t)(start + j + 1) * 128 + d0));
            u16x4 g2 = __builtin_nontemporal_load((const u16x4*)(eab + (size_t)(start + j + 2) * 128 + d0));
            u16x4 g3 = __builtin_nontemporal_load((const u16x4*)(eab + (size_t)(start + j + 3) * 128 + d0));
            f32x4 a0, a1, a2, a3;
#pragma unroll
            for (int q = 0; q < 4; ++q) {
                a0[q] = bf2f(g0[q]); a1[q] = bf2f(g1[q]);
                a2[q] = bf2f(g2[q]); a3[q] = bf2f(g3[q]);
            }
            APPLY(x0, a0); APPLY(x1, a1); APPLY(x2, a2); APPLY(x3, a3);
        }
        for (; j < hi; ++j) {
            int2 e0 = el[start + j];
            u16x4 x0 = *(const u16x4*)(xb + (size_t)e0.x * 128 + d0);
            u16x4 g0 = __builtin_nontemporal_load((const u16x4*)(eab + (size_t)(start + j) * 128 + d0));
            f32x4 a0;
#pragma unroll
            for (int q = 0; q < 4; ++q) a0[q] = bf2f(g0[q]);
            APPLY(x0, a0);
        }
    }
#undef APPLY

    // combine the two half-wave partial sums
#pragma unroll
    for (int q = 0; q < 4; ++q) acc[q] += __shfl_xor(acc[q], 32);

    if (half == 0) {
        u16x4 o;
        o[0] = f2bf(acc[0]); o[1] = f2bf(acc[1]);
        o[2] = f2bf(acc[2]); o[3] = f2bf(acc[3]);
        *(u16x4*)(t1 + (size_t)n * 128 + d0) = o;
    }
}

// ---------------- GEMM 128x128 tile, 8 waves, fused BN-affine + col stats
// out[n][c] = sum_k a[n][k]*Wt[c][k] + bias[c].  Wt bf16 [c][k]; inp bf16.
// BNA: a = bf16(relu(inp*sc+sh)); else a = inp.
// OUTBF: out stored bf16, else f32. Stats accumulate on pre-round f32 values.
template<bool BNA, bool OUTBF>
__global__ __launch_bounds__(512) void gemm_kernel(
    const unsigned short* __restrict__ inp,   // [N][128] bf16
    const unsigned short* __restrict__ Wt,    // [128][128] bf16, [c][k]
    const float* __restrict__ bias,           // [128] f32
    const float* __restrict__ statsIn,
    const float* __restrict__ gA, const float* __restrict__ bA,
    void* __restrict__ outv, float* __restrict__ statsOut, int N)
{
    __shared__ __attribute__((aligned(16))) unsigned short As[128][136];  // [r][k]
    __shared__ __attribute__((aligned(16))) unsigned short Ws[128][136];  // [c][k]
    __shared__ float u0[128], u1[128];  // BNA: sc/sh during staging; then stats
    const int tid = threadIdx.x;
    const int row0 = blockIdx.x * 128;

    if (BNA) {
        if (tid < 128) {
            float inv = 1.f / (float)N;
            float m = statsIn[tid] * inv;
            float v = statsIn[128 + tid] * inv - m * m;
            v = fmaxf(v, 0.f);
            float rs = rsqrtf(v + 1e-5f);
            float gr = gA[tid] * rs;
            u0[tid] = gr;
            u1[tid] = bA[tid] - m * gr;
        }
        __syncthreads();
    }

    // stage Wt -> Ws: 16384 elems, 512 thr x 8 elems x 4 iters
#pragma unroll
    for (int it = 0; it < 4; ++it) {
        int lin = (it * 512 + tid) * 8;
        int c = lin >> 7;
        int k = lin & 127;
        *(uint4*)&Ws[c][k] = *(const uint4*)(Wt + (size_t)c * 128 + k);
    }
    // stage A tile: 128x128 bf16, 4 iters (zero-pad tail rows)
#pragma unroll
    for (int it = 0; it < 4; ++it) {
        int lin = (it * 512 + tid) * 8;
        int r = lin >> 7;
        int c = lin & 127;
        int row = row0 + r;
        if (row < N) {
            uint4 v = *(const uint4*)(inp + (size_t)row * 128 + c);
            if (BNA) {
                const unsigned short* pv = (const unsigned short*)&v;
                unsigned short o[8];
#pragma unroll
                for (int q = 0; q < 8; ++q)
                    o[q] = f2bf(fmaxf(fmaf(bf2f(pv[q]), u0[c + q], u1[c + q]), 0.f));
                *(uint4*)&As[r][c] = *(const uint4*)o;
            } else {
                *(uint4*)&As[r][c] = v;
            }
        } else {
            uint4 z = {0u, 0u, 0u, 0u};
            *(uint4*)&As[r][c] = z;
        }
    }
    __syncthreads();
    // repurpose u0/u1 as column sum / sumsq accumulators
    if (tid < 128) { u0[tid] = 0.f; u1[tid] = 0.f; }
    __syncthreads();

    const int wave = tid >> 6;          // 0..7, owns rows wave*16..+15
    const int lane = tid & 63;
    const int quad = lane >> 4;
    const int m16  = lane & 15;

    bf16x8 af[4];
#pragma unroll
    for (int kk = 0; kk < 4; ++kk)
        af[kk] = *reinterpret_cast<const bf16x8*>(
            &As[wave * 16 + m16][kk * 32 + quad * 8]);

    float* outf = (float*)outv;
    unsigned short* outb = (unsigned short*)outv;

#pragma unroll
    for (int ct = 0; ct < 8; ++ct) {
        f32x4 acc = {0.f, 0.f, 0.f, 0.f};
#pragma unroll
        for (int kk = 0; kk < 4; ++kk) {
            bf16x8 bf = *reinterpret_cast<const bf16x8*>(&Ws[ct * 16 + m16][kk * 32 + quad * 8]);
            acc = __builtin_amdgcn_mfma_f32_16x16x32_bf16(af[kk], bf, acc, 0, 0, 0);
        }
        int col = ct * 16 + m16;
        float bb = bias[col];
        float s_part = 0.f, q_part = 0.f;
#pragma unroll
        for (int r = 0; r < 4; ++r) {
            int row = row0 + wave * 16 + quad * 4 + r;  // C/D: row = quad*4+reg
            if (row < N) {
                float val = acc[r] + bb;
                if (OUTBF) outb[(size_t)row * 128 + col] = f2bf(val);
                else       outf[(size_t)row * 128 + col] = val;
                s_part += val;
                q_part += val * val;
            }
        }
        // reduce over the 4 quad-groups that share this column (lanes ^16, ^32)
        s_part += __shfl_xor(s_part, 16); q_part += __shfl_xor(q_part, 16);
        s_part += __shfl_xor(s_part, 32); q_part += __shfl_xor(q_part, 32);
        if (lane < 16) {
            atomicAdd(&u0[col], s_part);
            atomicAdd(&u1[col], q_part);
        }
    }
    __syncthreads();
    if (tid < 128) {
        atomicAdd(&statsOut[tid],       u0[tid]);
        atomicAdd(&statsOut[128 + tid], u1[tid]);
    }
}

// out = gamma * (t - mean) * rsqrt(var + eps) + beta  (final layer, no relu)
__global__ __launch_bounds__(256) void bn_kernel(
    const float* __restrict__ t, const float* __restrict__ sum, const float* __restrict__ sq,
    const float* __restrict__ gamma, const float* __restrict__ beta,
    float* __restrict__ out, int N, int nv4)
{
    __shared__ float sc[128], sh[128];
    int tid = threadIdx.x;
    if (tid < 128) {
        float inv = 1.f / (float)N;
        float m = sum[tid] * inv;
        float v = sq[tid] * inv - m * m;
        v = fmaxf(v, 0.f);
        float rs = rsqrtf(v + 1e-5f);
        float gr = gamma[tid] * rs;
        sc[tid] = gr;
        sh[tid] = beta[tid] - m * gr;
    }
    __syncthreads();
    int g = blockIdx.x * 256 + tid;
    if (g < nv4) {
        int c = (g & 31) * 4;
        float4 v = *(const float4*)(t + (size_t)g * 4);
        float4 o;
        o.x = v.x * sc[c + 0] + sh[c + 0];
        o.y = v.y * sc[c + 1] + sh[c + 1];
        o.z = v.z * sc[c + 2] + sh[c + 2];
        o.w = v.w * sc[c + 3] + sh[c + 3];
        *(float4*)(out + (size_t)g * 4) = o;
    }
}

extern "C" void kernel_launch(void* const* d_in, const int* in_sizes, int n_in,
                              void* d_out, int out_size, void* d_ws, size_t ws_size,
                              hipStream_t stream)
{
    const float* x  = (const float*)d_in[0];
    const int* ei   = (const int*)d_in[1];
    const float* ea = (const float*)d_in[2];
    // d_in[3] = batch (unused)
    const float* W1 = (const float*)d_in[4];
    const float* b1 = (const float*)d_in[5];
    const float* gm = (const float*)d_in[6];
    const float* bm = (const float*)d_in[7];
    const float* W2 = (const float*)d_in[8];
    const float* b2 = (const float*)d_in[9];
    const float* go = (const float*)d_in[10];
    const float* bo = (const float*)d_in[11];
    float* out = (float*)d_out;

    const int N = in_sizes[0] / 128;   // 50000
    const int E = in_sizes[2] / 128;   // 800000

    char* w = (char*)d_ws;
    float* t3f  = (float*)w;            w += (size_t)N * 128 * 4;   // layer-2 gemm2 out, f32
    unsigned short* t3b = (unsigned short*)w; w += (size_t)N * 128 * 2;  // layers 0/1 gemm2 out
    unsigned short* t1 = (unsigned short*)w; w += (size_t)N * 128 * 2;  // agg out, bf16
    unsigned short* t2 = (unsigned short*)w; w += (size_t)N * 128 * 2;  // gemm1 out, bf16
    unsigned short* xb = (unsigned short*)w; w += (size_t)N * 128 * 2;  // x bf16 (layer 0)
    unsigned short* Wt = (unsigned short*)w; w += (size_t)6 * 16384 * 2; // W bf16 [c][k]
    float* stats = (float*)w;           w += 1536 * 4;              // 6 x (sum[128], sq[128])
    int* i64flag = (int*)w;             w += 16;
    int* counts  = (int*)w;             w += (size_t)N * 4;
    int* offs    = (int*)w;             w += (size_t)(N + 16) * 4;  // N+1 entries
    int* cursor  = (int*)w;             w += (size_t)N * 4;
    int* bsum    = (int*)w;             w += 256 * 4;
    int2* el     = (int2*)w;            w += (size_t)E * 8;         // CSR: (src, edge)
    unsigned short* eab = (unsigned short*)w; w += (size_t)E * 128 * 2;  // ea bf16, CSR order

    const int nv4 = N * 32;
    const int gElem = (nv4 + 255) / 256;
    const int gGemm = (N + 127) / 128;
    const int gEdge = (E + 255) / 256;
    const int nb    = (N + 255) / 256;
    const int gAgg  = (N + 7) / 8;
    const int gConv = (N * 16 + 255) / 256;
    const int gSetup = gConv > nb ? gConv : nb;

    // ---- CSR build + W/x pre-convert (all layer-invariant) ----
    setup_kernel<<<gSetup, 256, 0, stream>>>(ei, i64flag, counts, stats, W1, W2, Wt, x, xb, N);
    hist_kernel<<<gEdge, 256, 0, stream>>>(ei, i64flag, counts, E);
    scan1_kernel<<<nb, 256, 0, stream>>>(counts, offs, bsum, N);
    scan23_kernel<<<nb, 256, 0, stream>>>(offs, bsum, cursor, N, E, nb);
    scatter_kernel<<<gEdge, 256, 0, stream>>>(ei, i64flag, cursor, el, E);

    for (int i = 0; i < 3; ++i) {
        float* sMlp = stats + (size_t)i * 512;        // gemm1 output stats
        float* sOut = stats + (size_t)i * 512 + 256;  // gemm2 output stats

        if (i == 0) {
            // layer 0: f32 ea via el[].y; also materializes eab in CSR order
            agg_kernel<0><<<gAgg, 512, 0, stream>>>(
                xb, ea, eab, el, offs, nullptr, nullptr, nullptr, t1, N);
        } else {
            float* sPrev = stats + (size_t)(i - 1) * 512 + 256;
            // layers 1-2: stream eab (bf16, sequential by slot)
            agg_kernel<1><<<gAgg, 512, 0, stream>>>(
                t3b, nullptr, eab, el, offs, sPrev, go + (i - 1) * 128, bo + (i - 1) * 128, t1, N);
        }
        // gemm1: t1 (bf16) -> t2 (bf16), stats of t2 -> sMlp
        gemm_kernel<false, true><<<gGemm, 512, 0, stream>>>(
            t1, Wt + (size_t)i * 16384, b1 + i * 128,
            nullptr, nullptr, nullptr, t2, sMlp, N);
        // gemm2: BN1+relu applied to t2; layers 0/1 -> t3b (bf16), layer 2 -> t3f (f32)
        if (i < 2) {
            gemm_kernel<true, true><<<gGemm, 512, 0, stream>>>(
                t2, Wt + (size_t)(i + 3) * 16384, b2 + i * 128,
                sMlp, gm + i * 128, bm + i * 128, t3b, sOut, N);
        } else {
            gemm_kernel<true, false><<<gGemm, 512, 0, stream>>>(
                t2, Wt + (size_t)(i + 3) * 16384, b2 + i * 128,
                sMlp, gm + i * 128, bm + i * 128, t3f, sOut, N);
        }
    }
    // final outer BN (no relu) -> out
    bn_kernel<<<gElem, 256, 0, stream>>>(t3f, stats + 2 * 512 + 256, stats + 2 * 512 + 384,
                                         go + 256, bo + 256, out, N, nv4);
}